// Round 8
// baseline (3165.627 us; speedup 1.0000x reference)
//
#include <hip/hip_runtime.h>
#include <cmath>

typedef __attribute__((ext_vector_type(8))) short short8;
typedef __attribute__((ext_vector_type(4))) float f32x4;

#define NB 32
#define NS 64
#define NK 5
#define NE 512
#define NH 512
#define C1V 2500
#define C2V 10000
#define CSZ1V 7500
#define CSZ2V 40000

// ---- workspace BYTE offsets ----
#define PWR_B   0u          // 4*512*512 f32 = 4MB (preamble only; aliased by ghE)
#define GHE_B   0u          // 64*2048*32 bf16 = 8MB
#define QB_B    8388608u    // 32*512 bf16
#define H1B_B   8421376u
#define H0B_B   8454144u
#define PHI_B   8488192u    // 160 f32
#define P1_B    8488832u    // 2048*128 f32
#define P2_B    9537408u    // 2048*32 f32
#define SUMS_B  9799552u    // 3*2048 f32
#define HLT_B   9824128u
#define HC1_B   9832320u
#define HC2_B   9840512u
#define L1P_B   9848704u
#define L2P_B   9856896u
#define BAR_B   9865216u    // preamble flags 208*64B = 13312, go at +13312; memset 16384
#define SB2_B   9881600u    // 80*32 f32 score partials; end 9,891,840
#define CTR_B   9891840u    // scan counters: A[t] +0, C[t] +4096, D[t] +8192; 12288 B; end 9,904,128

// ---- d_out float offsets (verified) ----
#define O_LP   0
#define O_LOSS 2048
#define O_OUTS 2049
#define O_HF   1050625
#define O_CF   1083393
#define O_ATTN 1116161
#define O_COVF 1126401

// ---- LDS byte offsets (scan kernel) ----
#define ROWB 1040           // 520 bf16 per padded row (mult of 16 for b128 loads)
#define L_W1  0
#define L_WI  16640
#define L_W0  33280
#define L_ACT 49920
#define L_TP  83200
#define L_GH1 93440
#define L_GH0 95488
#define L_GB  97536
#define L_AL  99584
#define LDS_BYTES 100352
#define A_MI  0
#define A_ACT 33280
#define A_SCR 66560

__device__ __forceinline__ float sigmf(float x){ return 1.0f/(1.0f + expf(-x)); }

__device__ __forceinline__ unsigned short f2b16(float f){
  unsigned u = __float_as_uint(f);
  return (unsigned short)((u + 0x7fffu + ((u>>16)&1u)) >> 16);
}
__device__ __forceinline__ float b2f16(unsigned short s){ return __uint_as_float(((unsigned)s)<<16); }

// pack 4 f32 -> 4 bf16 in a u64
__device__ __forceinline__ unsigned long long pk4(float4 v){
  unsigned long long u = (unsigned long long)f2b16(v.x)
    | ((unsigned long long)f2b16(v.y) << 16)
    | ((unsigned long long)f2b16(v.z) << 32)
    | ((unsigned long long)f2b16(v.w) << 48);
  return u;
}

// ---- agent-scope (coherence-point) primitives ----
__device__ __forceinline__ unsigned ldf(unsigned* p){
  return __hip_atomic_load(p, __ATOMIC_RELAXED, __HIP_MEMORY_SCOPE_AGENT);
}
__device__ __forceinline__ void stf(unsigned* p, unsigned v){
  __hip_atomic_store(p, v, __ATOMIC_RELAXED, __HIP_MEMORY_SCOPE_AGENT);
}
__device__ __forceinline__ void sta64(unsigned long long* p, unsigned long long v){
  __hip_atomic_store(p, v, __ATOMIC_RELAXED, __HIP_MEMORY_SCOPE_AGENT);
}
__device__ __forceinline__ unsigned long long lda64(const unsigned long long* p){
  return __hip_atomic_load((unsigned long long*)p, __ATOMIC_RELAXED, __HIP_MEMORY_SCOPE_AGENT);
}
__device__ __forceinline__ void staf(float* p, float v){
  __hip_atomic_store(p, v, __ATOMIC_RELAXED, __HIP_MEMORY_SCOPE_AGENT);
}
__device__ __forceinline__ float ldaf(const float* p){
  return __hip_atomic_load((float*)p, __ATOMIC_RELAXED, __HIP_MEMORY_SCOPE_AGENT);
}
__device__ __forceinline__ void ctr_add(unsigned* c){
  __hip_atomic_fetch_add(c, 1u, __ATOMIC_RELAXED, __HIP_MEMORY_SCOPE_AGENT);
}

// ---- heavy barrier (preamble only) ----
__device__ __forceinline__ void bar_arrive(unsigned* flags, int wg, unsigned gen, int tid){
  __syncthreads();
  if (tid == 0){
    __threadfence();
    stf(flags + wg*16, gen);
  }
}
__device__ __forceinline__ void bar_collect(unsigned* flags, unsigned* go, unsigned gen,
                                            int first, int cnt, int tid){
  for (int i = tid; i < cnt; i += 256){
    unsigned* f = flags + (first + i)*16;
    while (ldf(f) < gen) __builtin_amdgcn_s_sleep(1);
  }
  __syncthreads();
  if (tid == 0) stf(go, gen);
}
__device__ __forceinline__ void bar_wait(unsigned* go, unsigned gen, int tid){
  if (tid == 0){
    while (ldf(go) < gen) __builtin_amdgcn_s_sleep(1);
    __threadfence();
  }
  __syncthreads();
}

// ---- scan-loop sync: single-counter barrier (1 poller, 1 line) ----
// Producer protocol: data stores (agent-scope) -> __syncthreads() (vmcnt drain:
// stores complete at coherence point) -> tid0 ctr_add. Consumer: tid0 polls the
// counter to target, __syncthreads releases wg; data then read with agent loads.
__device__ __forceinline__ void waitctr(unsigned* c, unsigned tgt, int tid){
  if (tid == 0){
    while (ldf(c) < tgt) __builtin_amdgcn_s_sleep(1);
  }
  __syncthreads();
}

// D[m][n] += A[m][k]*B[n][k] over K=512, one 16x16 tile, rows padded ROWB.
__device__ __forceinline__ f32x4 chain16(const char* Abase, const char* Bbase, int lane){
  f32x4 acc = {0.f,0.f,0.f,0.f};
  int lr = lane & 15, lq = lane >> 4;
  const char* ap = Abase + lr*ROWB + lq*16;
  const char* bp = Bbase + lr*ROWB + lq*16;
  #pragma unroll
  for (int ks=0; ks<16; ks++){
    short8 af = *(const short8*)(ap + ks*64);
    short8 bf = *(const short8*)(bp + ks*64);
    acc = __builtin_amdgcn_mfma_f32_16x16x32_bf16(af, bf, acc, 0, 0, 0);
  }
  return acc;
}

// generic-stride, generic-K chain: K = nks*32. strides must be multiples of 16B.
__device__ __forceinline__ f32x4 chainT(const char* Abase, const char* Bbase,
                                        int sA, int sB, int nks, int lane){
  f32x4 acc = {0.f,0.f,0.f,0.f};
  int lr = lane & 15, lq = lane >> 4;
  const char* ap = Abase + lr*sA + lq*16;
  const char* bp = Bbase + lr*sB + lq*16;
  for (int ks=0; ks<nks; ks++){
    short8 af = *(const short8*)(ap + ks*64);
    short8 bf = *(const short8*)(bp + ks*64);
    acc = __builtin_amdgcn_mfma_f32_16x16x32_bf16(af, bf, acc, 0, 0, 0);
  }
  return acc;
}

__device__ __forceinline__ void stage32(const unsigned short* g, char* dst, int tid){
  int b = tid & 31, seg = tid >> 5;
  const float4* s4 = (const float4*)(g + (size_t)b*512 + seg*64);
  float4* d4 = (float4*)(dst + b*ROWB + seg*128);
  #pragma unroll
  for (int i=0;i<8;i++) d4[i] = s4[i];
}

// agent-scope variant used inside the scan loop
__device__ __forceinline__ void stage32a(const unsigned short* g, char* dst, int tid){
  int b = tid & 31, seg = tid >> 5;
  const unsigned long long* s8 = (const unsigned long long*)(g + (size_t)b*512 + seg*64);
  unsigned long long* d8 = (unsigned long long*)(dst + b*ROWB + seg*128);
  #pragma unroll
  for (int i=0;i<16;i++) d8[i] = lda64(s8 + i);
}

__device__ __forceinline__ float dot512(const float* __restrict__ x, const float* __restrict__ w){
  const float4* x4 = (const float4*)x;
  const float4* w4 = (const float4*)w;
  float a0=0.f,a1=0.f,a2=0.f,a3=0.f;
  #pragma unroll 8
  for (int h=0; h<128; h++){
    float4 xx = x4[h]; float4 ww = w4[h];
    a0 = fmaf(xx.x, ww.x, a0); a1 = fmaf(xx.y, ww.y, a1);
    a2 = fmaf(xx.z, ww.z, a2); a3 = fmaf(xx.w, ww.w, a3);
  }
  return (a0+a1)+(a2+a3);
}

struct ScanArgs {
  const int* inputs; const int* topics; const float* out0;
  const float* h0in; const float* c0in; const float* mask; const float* cover;
  const float* emb; const float* Uf; const float* Ua; const float* Wa;
  const float* vaw; const float* vab;
  const float* wih0; const float* whh0; const float* bih0; const float* bhh0;
  const float* wih1; const float* whh1; const float* bih1; const float* bhh1;
  char* ws; float* out;
};

// ====================== scan kernel (round-1 structure; flag-walls -> counters) ======================
// 208 wgs x 256 threads. wgs 0..79 attention (wg0 = preamble collector), 80..207 LSTM.
__global__ __launch_bounds__(256) void scan_kernel(ScanArgs a){
  extern __shared__ char sm[];
  const int wg = blockIdx.x, tid = threadIdx.x;
  const int lane = tid & 63, wave = tid >> 6;
  const int GT = gridDim.x * blockDim.x;
  const int gt = wg*256 + tid;
  char* wsb = a.ws;
  unsigned* bflags = (unsigned*)(wsb + BAR_B);
  unsigned* bgo    = (unsigned*)(wsb + BAR_B + 13312);
  unsigned* ctrA   = (unsigned*)(wsb + CTR_B);
  unsigned* ctrC   = (unsigned*)(wsb + CTR_B + 4096);
  unsigned* ctrD   = (unsigned*)(wsb + CTR_B + 8192);
  const bool isAttn = (wg < 80);
  const int head = wg >> 4;
  const int e0 = (wg & 15) * 32;
  const int lw = wg - 80;
  const int u0 = lw * 4;

  f32x4 pkr = {0.f,0.f,0.f,0.f};
  float var[4] = {0.f,0.f,0.f,0.f};
  float b0r[4] = {0,0,0,0}, b1r[4] = {0,0,0,0};
  float c0r = 0.f, c1r = 0.f;
  float covr[NK] = {0,0,0,0,0}, phir[NK] = {1,1,1,1,1};

  // ================= P0a: inits + phi =================
  {
    unsigned short* qb  = (unsigned short*)(wsb + QB_B);
    unsigned short* h1b = (unsigned short*)(wsb + H1B_B);
    unsigned short* h0b = (unsigned short*)(wsb + H0B_B);
    for (int i = gt; i < NB*NH; i += GT){
      qb[i]  = f2b16(a.out0[i]);
      h1b[i] = f2b16(a.h0in[NB*NH + i]);
      h0b[i] = f2b16(a.h0in[i]);
    }
    if (gt < 160){
      int b = gt/NK, k = gt%NK;
      float ms = 0.f; for (int s=0;s<NS;s++) ms += a.mask[b*NS+s];
      float acc = 0.f;
      for (int kk=0; kk<NK; kk++){
        const float* te = a.emb + (size_t)a.topics[b*NK+kk]*NE;
        const float* uf = a.Uf + (size_t)k*(NK*NE) + kk*NE;
        acc += dot512(te, uf);
      }
      ((float*)(wsb + PHI_B))[gt] = ms * sigmf(acc);
    }
  }
  bar_arrive(bflags, wg, 1, tid);
  if (wg==0) bar_collect(bflags, bgo, 1, 0, 208, tid);
  bar_wait(bgo, 1, tid);

  // ================= P1: Wa powers (fp32) =================
  for (int r=0; r<4; r++){
    const float* Asrc = (r==0) ? a.Wa : (const float*)(wsb + PWR_B) + (size_t)(r-1)*NH*NH;
    float* Mo = (float*)(wsb + PWR_B) + (size_t)r*NH*NH;
    for (int d = gt; d < NH*NH; d += GT){
      int row = d >> 9, col = d & 511;
      const float* ar = Asrc + (size_t)row*NH;
      float acc = 0.f;
      for (int k2=0;k2<NH;k2++) acc = fmaf(ar[k2], a.Wa[(size_t)k2*NH + col], acc);
      Mo[d] = acc;
    }
    unsigned g = 2 + r;
    bar_arrive(bflags, wg, g, tid);
    if (wg==0) bar_collect(bflags, bgo, g, 0, 208, tid);
    bar_wait(bgo, g, tid);
  }

  // ================= P2: attn pk+Mi; lstm tp =================
  if (isAttn){
    for (int idx=tid; idx<32*512; idx+=256){
      int r = idx>>9, k = idx&511;
      *(unsigned short*)(sm + A_MI + r*ROWB + k*2) = f2b16(a.Ua[(size_t)(e0+r)*NE + k]);
    }
    for (int idx=tid; idx<32*512; idx+=256){
      int r = idx>>9, k = idx&511;
      int tok = a.topics[r*NK + head];
      *(unsigned short*)(sm + A_ACT + r*ROWB + k*2) = f2b16(a.emb[(size_t)tok*NE + k]);
    }
    __syncthreads();
    {
      int mt = wave&1, nt = wave>>1;
      pkr = chain16(sm + A_MI + mt*16*ROWB, sm + A_ACT + nt*16*ROWB, lane);
      int lq = lane>>4;
      #pragma unroll
      for (int r2=0;r2<4;r2++) var[r2] = a.vaw[e0 + mt*16 + lq*4 + r2];
    }
    __syncthreads();
    const float* Msrc = (head==0) ? a.Wa : (const float*)(wsb + PWR_B) + (size_t)(head-1)*NH*NH;
    for (int idx=tid; idx<32*512; idx+=256){
      int r = idx>>9, k = idx&511;
      *(unsigned short*)(sm + A_MI + r*ROWB + k*2) = f2b16(Msrc[(size_t)(e0+r)*NH + k]);
    }
  } else {
    for (int idx=tid; idx<16*512; idx+=256){
      int rr = idx>>9, k = idx&511;
      int j = (rr>>2)*NH + u0 + (rr&3);
      *(unsigned short*)(sm + L_WI + rr*ROWB + k*2) = f2b16(a.wih0[(size_t)j*(2*NE) + NE + k]);
    }
    __syncthreads();
    for (int rnd=0; rnd<5; rnd++){
      for (int idx=tid; idx<32*512; idx+=256){
        int r = idx>>9, k = idx&511;
        int tok = a.topics[rnd*32 + r];
        *(unsigned short*)(sm + L_ACT + r*ROWB + k*2) = f2b16(a.emb[(size_t)tok*NE + k]);
      }
      __syncthreads();
      if (wave < 2){
        f32x4 acc = chain16(sm + L_ACT + wave*16*ROWB, sm + L_WI, lane);
        int lr = lane&15, lq = lane>>4;
        #pragma unroll
        for (int r2=0;r2<4;r2++){
          int row = rnd*32 + wave*16 + lq*4 + r2;
          int bb = row/5, kk = row - bb*5;
          *(float*)(sm + L_TP + (((kk*16) + lr)*32 + bb)*4) = acc[r2];
        }
      }
      __syncthreads();
    }
  }
  // g6: attn done reading powers -> lstm may overwrite with ghE
  bar_arrive(bflags, wg, 6, tid);
  if (wg==0) bar_collect(bflags, bgo, 6, 0, 208, tid);
  if (!isAttn) bar_wait(bgo, 6, tid);

  // ================= P4 (lstm only): ghE + weights + regs + gh0 init =================
  if (!isAttn){
    for (int idx=tid; idx<16*512; idx+=256){
      int rr = idx>>9, k = idx&511;
      int j = (rr>>2)*NH + u0 + (rr&3);
      *(unsigned short*)(sm + 66560 + rr*ROWB + k*2) = f2b16(a.wih0[(size_t)j*(2*NE) + k]);
    }
    __syncthreads();
    unsigned short* gE = (unsigned short*)(wsb + GHE_B);
    for (int it=0; it<32; it++){
      for (int idx=tid; idx<64*512; idx+=256){
        int r = idx>>9, k = idx&511;
        int grow = it*64 + r;
        int tt = grow>>5, bb = grow&31;
        int tok = a.inputs[bb*NS + tt];
        *(unsigned short*)(sm + r*ROWB + k*2) = f2b16(a.emb[(size_t)tok*NE + k]);
      }
      __syncthreads();
      {
        f32x4 acc = chain16(sm + wave*16*ROWB, sm + 66560, lane);
        int lr = lane&15, lq = lane>>4;
        #pragma unroll
        for (int r2=0;r2<4;r2++){
          int grow = it*64 + wave*16 + lq*4 + r2;
          int tt = grow>>5, bb = grow&31;
          int jg = (lr>>2)*NH + u0 + (lr&3);
          gE[((size_t)tt*2048 + jg)*32 + bb] = f2b16(acc[r2]);
        }
      }
      __syncthreads();
    }
    for (int idx=tid; idx<16*512; idx+=256){
      int rr = idx>>9, k = idx&511;
      int j = (rr>>2)*NH + u0 + (rr&3);
      *(unsigned short*)(sm + L_W1 + rr*ROWB + k*2) = f2b16(a.whh1[(size_t)j*NH + k]);
      *(unsigned short*)(sm + L_WI + rr*ROWB + k*2) = f2b16(a.wih1[(size_t)j*NH + k]);
      *(unsigned short*)(sm + L_W0 + rr*ROWB + k*2) = f2b16(a.whh0[(size_t)j*NH + k]);
    }
    if (tid < 128){
      int bb = tid&31, ur = tid>>5;
      #pragma unroll
      for (int g=0; g<4; g++){
        int j = g*NH + u0 + ur;
        b0r[g] = a.bih0[j] + a.bhh0[j];
        b1r[g] = a.bih1[j] + a.bhh1[j];
      }
      c0r = a.c0in[(size_t)bb*NH + u0 + ur];
      c1r = a.c0in[(size_t)NB*NH + bb*NH + u0 + ur];
    }
    if (tid < 32){
      const float* phiG = (const float*)(wsb + PHI_B);
      #pragma unroll
      for (int k=0;k<NK;k++){ covr[k] = a.cover[tid*NK + k]; phir[k] = phiG[tid*NK + k]; }
    }
    __syncthreads();
    stage32((const unsigned short*)(wsb + H0B_B), sm + L_ACT, tid);
    __syncthreads();
    if (wave & 1){
      int nt = wave>>1;
      f32x4 acc = chain16(sm + L_W0, sm + L_ACT + nt*16*ROWB, lane);
      int lr = lane&15, lq = lane>>4;
      #pragma unroll
      for (int r2=0;r2<4;r2++)
        *(float*)(sm + L_GH0 + ((lq*4+r2)*32 + nt*16 + lr)*4) = acc[r2];
    }
    __syncthreads();
  }

  // ================= scan: counter-walled phases (same ordering proof as flags) =================
  // ctrA[t]==80 : scores(t) published. ctrC[t]==128 : h0(t) published.
  // ctrD[t]==128: h1(t) published (end of iteration t).
  for (int t=0; t<NS; t++){
    if (isAttn){
      if (t) waitctr(ctrD + (t-1)*16, 128, tid); else __syncthreads();
      stage32a((const unsigned short*)(wsb + QB_B), sm + A_ACT, tid);
      __syncthreads();
      int mt = wave&1, nt = wave>>1;
      f32x4 acc = chain16(sm + A_MI + mt*16*ROWB, sm + A_ACT + nt*16*ROWB, lane);
      float v = 0.f;
      #pragma unroll
      for (int r2=0;r2<4;r2++) v += tanhf(acc[r2] + pkr[r2]) * var[r2];
      v += __shfl_xor(v, 16);
      v += __shfl_xor(v, 32);
      if ((lane>>4)==0) *(float*)(sm + A_SCR + (wave*16 + (lane&15))*4) = v;
      __syncthreads();
      if (tid < 32){
        int nt2 = tid>>4, bh = tid&15;
        float s = *(const float*)(sm + A_SCR + ((nt2*2)*16 + bh)*4)
                + *(const float*)(sm + A_SCR + ((nt2*2+1)*16 + bh)*4);
        staf(((float*)(wsb + SB2_B)) + wg*32 + tid, s);
      }
      __syncthreads();                                // drains agent stores
      if (tid == 0) ctr_add(ctrA + t*16);             // publish scores(t)
    } else {
      if (t) waitctr(ctrD + (t-1)*16, 128, tid); else __syncthreads();
      stage32a((const unsigned short*)(wsb + H1B_B), sm + L_ACT, tid);
      __syncthreads();
      if (wave < 2){
        f32x4 acc = chain16(sm + L_W1, sm + L_ACT + wave*16*ROWB, lane);
        int lr = lane&15, lq = lane>>4;
        #pragma unroll
        for (int r2=0;r2<4;r2++)
          *(float*)(sm + L_GH1 + ((lq*4+r2)*32 + wave*16 + lr)*4) = acc[r2];
      }
      waitctr(ctrA + t*16, 80, tid);                  // scores(t) ready

      // ---- Phase C ----
      if (tid < 160){
        int k = tid>>5, b = tid&31;
        const float* sb2 = (const float*)(wsb + SB2_B);
        float s = 0.f;
        #pragma unroll
        for (int es=0; es<16; es++) s += ldaf(sb2 + (k*16+es)*32 + b);
        *(float*)(sm + L_GB + tid*4) = s;
      }
      __syncthreads();
      if (tid < 32){
        float vb = a.vab[0];
        float sc[NK], mx = -1e30f;
        #pragma unroll
        for (int k=0;k<NK;k++){
          float s = (*(const float*)(sm + L_GB + (k*32+tid)*4) + vb) * covr[k];
          sc[k] = s; mx = fmaxf(mx, s);
        }
        float sum = 0.f;
        #pragma unroll
        for (int k=0;k<NK;k++){ sc[k] = expf(sc[k]-mx); sum += sc[k]; }
        float inv = 1.0f/sum;
        #pragma unroll
        for (int k=0;k<NK;k++){
          float al = sc[k]*inv;
          *(float*)(sm + L_AL + (tid*NK+k)*4) = al;
          covr[k] = covr[k] - al/phir[k];
          if (lw == 0){
            a.out[O_ATTN + (size_t)(t*NB + tid)*NK + k] = al;
            if (t == NS-1) a.out[O_COVF + tid*NK + k] = covr[k];
          }
        }
      }
      __syncthreads();
      if (tid < 128){
        int bb = tid&31, ur = tid>>5;
        const unsigned short* gE = (const unsigned short*)(wsb + GHE_B);
        float al[NK];
        #pragma unroll
        for (int k=0;k<NK;k++) al[k] = *(const float*)(sm + L_AL + (bb*NK+k)*4);
        float g4[4];
        #pragma unroll
        for (int g=0; g<4; g++){
          int rr = g*4 + ur;
          float x = b2f16(gE[((size_t)t*2048 + g*NH + u0 + ur)*32 + bb]);
          x += *(const float*)(sm + L_GH0 + (rr*32 + bb)*4);
          x += b0r[g];
          #pragma unroll
          for (int k=0;k<NK;k++) x += al[k] * *(const float*)(sm + L_TP + ((k*16+rr)*32 + bb)*4);
          g4[g] = x;
        }
        float cn = sigmf(g4[1])*c0r + sigmf(g4[0])*tanhf(g4[2]);
        float hn = sigmf(g4[3])*tanhf(cn);
        c0r = cn;
        ((unsigned short*)(sm + L_ACT))[bb*4 + ur] = f2b16(hn);
        if (t == NS-1){
          a.out[O_HF + (size_t)bb*NH + u0 + ur] = hn;
          a.out[O_CF + (size_t)bb*NH + u0 + ur] = cn;
        }
      }
      __syncthreads();
      if (tid < 32){
        unsigned long long v = *(const unsigned long long*)((const unsigned short*)(sm + L_ACT) + tid*4);
        sta64((unsigned long long*)((unsigned short*)(wsb + H0B_B) + (size_t)tid*NH + u0), v);
      }
      __syncthreads();                                // drains agent stores
      if (tid == 0) ctr_add(ctrC + t*16);             // publish h0 slice(t)
      waitctr(ctrC + t*16, 128, tid);                 // h0(t) fully published

      // ---- Phase D ----
      stage32a((const unsigned short*)(wsb + H0B_B), sm + L_ACT, tid);
      __syncthreads();
      {
        int mat = wave&1, nt = wave>>1;
        f32x4 acc = chain16(sm + (mat ? L_W0 : L_WI), sm + L_ACT + nt*16*ROWB, lane);
        int lr = lane&15, lq = lane>>4;
        char* dst = sm + (mat ? L_GH0 : L_GB);
        #pragma unroll
        for (int r2=0;r2<4;r2++)
          *(float*)(dst + ((lq*4+r2)*32 + nt*16 + lr)*4) = acc[r2];
      }
      __syncthreads();
      if (tid < 128){
        int bb = tid&31, ur = tid>>5;
        float g4[4];
        #pragma unroll
        for (int g=0; g<4; g++){
          int rr = g*4+ur;
          g4[g] = *(const float*)(sm + L_GB + (rr*32+bb)*4)
                + *(const float*)(sm + L_GH1 + (rr*32+bb)*4) + b1r[g];
        }
        float cn = sigmf(g4[1])*c1r + sigmf(g4[0])*tanhf(g4[2]);
        float hn = sigmf(g4[3])*tanhf(cn);
        c1r = cn;
        ((unsigned short*)(sm + L_ACT))[bb*4 + ur] = f2b16(hn);
        a.out[O_OUTS + (size_t)(t*NB + bb)*NH + u0 + ur] = hn;
        if (t == NS-1){
          a.out[O_HF + (size_t)(NB + bb)*NH + u0 + ur] = hn;
          a.out[O_CF + (size_t)(NB + bb)*NH + u0 + ur] = cn;
        }
      }
      __syncthreads();
      if (tid < 32){
        unsigned long long v = *(const unsigned long long*)((const unsigned short*)(sm + L_ACT) + tid*4);
        sta64((unsigned long long*)((unsigned short*)(wsb + QB_B)  + (size_t)tid*NH + u0), v);
        sta64((unsigned long long*)((unsigned short*)(wsb + H1B_B) + (size_t)tid*NH + u0), v);
      }
      __syncthreads();                                // drains agent stores
      if (tid == 0) ctr_add(ctrD + t*16);             // publish h1 slice(t)
    }
  }
}

// ================= adaptive log-softmax tail: MFMA GEMMs, column-split for TLP =================

// P1 = X @ t1w1.T, P2 = X @ t2w1.T  (round-1 kernel + y-split for occupancy)
__global__ __launch_bounds__(256) void kproj(const float* __restrict__ X,
                                             const float* __restrict__ t1w1,
                                             const float* __restrict__ t2w1,
                                             float* __restrict__ P1, float* __restrict__ P2){
  __shared__ float xs[16*516];
  int r0 = blockIdx.x*16, tid = threadIdx.x;
  int yy = blockIdx.y;
  for (int idx=tid; idx<16*512; idx+=256){ int rl=idx>>9, h=idx&511; xs[rl*516+h] = X[(size_t)(r0+rl)*NH + h]; }
  __syncthreads();
  if (yy == 0){
    for (int k=0;k<4;k++){
      int d = tid + 256*k; int rl = d & 15, c = d >> 4;
      P1[(size_t)(r0+rl)*128 + c] = dot512(xs + rl*516, t1w1 + (size_t)c*NH);
    }
  } else {
    for (int k=4;k<8;k++){
      int d = tid + 256*k; int rl = d & 15, c = d >> 4;
      P1[(size_t)(r0+rl)*128 + c] = dot512(xs + rl*516, t1w1 + (size_t)c*NH);
    }
    for (int k=0;k<2;k++){
      int d = tid + 256*k; int rl = d & 15, c = d >> 4;
      P2[(size_t)(r0+rl)*32 + c] = dot512(xs + rl*516, t2w1 + (size_t)c*NH);
    }
  }
}

// HEAD: logits = X(2048x512) @ hw.T(512x2502). Grid (64 row-blocks, 8 col-strips).
// Strip = 10 chunks x 32 cols (8*10*32 = 2560 >= 2504).
__global__ __launch_bounds__(256) void kheadM(const float* __restrict__ X,
                                              const float* __restrict__ hw,
                                              const int* __restrict__ tgt,
                                              float* __restrict__ sums,
                                              float* __restrict__ hlt, float* __restrict__ hc1,
                                              float* __restrict__ hc2){
  extern __shared__ char sm[];
  int* caps = (int*)(sm + 66560);
  int r0 = blockIdx.x*32, tid = threadIdx.x;
  int strip = blockIdx.y;
  int lane = tid&63, wave = tid>>6;
  int lr = lane&15, lq = lane>>4;
  // stage X rows (f32 -> bf16), vectorized
  #pragma unroll
  for (int it = 0; it < 16; it++){
    int idx = tid + it*256;
    int rl = idx>>7, h4 = idx&127;
    float4 v = *(const float4*)(X + (size_t)(r0+rl)*NH + h4*4);
    *(unsigned long long*)(sm + rl*ROWB + h4*8) = pk4(v);
  }
  if (tid < 32){
    int row = r0+tid;
    int tg = tgt[(row&31)*NS + (row>>5)];
    caps[tid] = tg < C1V ? tg : (C1V-1);
  }
  int mt = wave&1, nt = wave>>1;
  float exr[4] = {0.f,0.f,0.f,0.f};
  for (int ch = 0; ch < 10; ch++){
    int cc0 = (strip*10 + ch)*32;
    __syncthreads();                         // protect WT from previous iteration's readers
    #pragma unroll
    for (int it = 0; it < 16; it++){
      int idx = tid + it*256;
      int wr = idx>>7, h4 = idx&127;
      int col = cc0 + wr; if (col >= C1V+2) col = 0;
      float4 v = *(const float4*)(hw + (size_t)col*NH + h4*4);
      *(unsigned long long*)(sm + 33280 + wr*ROWB + h4*8) = pk4(v);
    }
    __syncthreads();
    f32x4 acc = chain16(sm + mt*16*ROWB, sm + 33280 + nt*16*ROWB, lane);
    int g = cc0 + nt*16 + lr;
    if (g < C1V+2){
      #pragma unroll
      for (int r2=0;r2<4;r2++){
        int row = mt*16 + lq*4 + r2;
        float v = acc[r2];
        exr[r2] += __expf(v);
        if (g == caps[row]) hlt[r0+row] = v;
        else if (g == C1V) hc1[r0+row] = v;
        else if (g == C1V+1) hc2[r0+row] = v;
      }
    }
  }
  #pragma unroll
  for (int r2=0;r2<4;r2++){
    float e = exr[r2];
    e += __shfl_xor(e,1); e += __shfl_xor(e,2); e += __shfl_xor(e,4); e += __shfl_xor(e,8);
    if (lr == 0) atomicAdd(&sums[r0 + mt*16 + lq*4 + r2], e);
  }
}

// TAIL1: logits = P1(2048x128) @ t1w2.T(128x7500). Grid (64, 8); strip = 30 chunks x 32 cols.
__global__ __launch_bounds__(256) void kt1M(const float* __restrict__ P1,
                                            const float* __restrict__ w2,
                                            const int* __restrict__ tgt,
                                            float* __restrict__ sums, float* __restrict__ l1p){
  __shared__ __align__(16) char pt[32*272];
  __shared__ __align__(16) char wt[32*272];
  __shared__ int t1c[32];
  int r0 = blockIdx.x*32, tid = threadIdx.x;
  int strip = blockIdx.y;
  int lane = tid&63, wave = tid>>6;
  int lr = lane&15, lq = lane>>4;
  #pragma unroll
  for (int it = 0; it < 4; it++){
    int idx = tid + it*256;
    int rl = idx>>5, h4 = idx&31;
    float4 v = *(const float4*)(P1 + (size_t)(r0+rl)*128 + h4*4);
    *(unsigned long long*)(pt + rl*272 + h4*8) = pk4(v);
  }
  if (tid < 32){
    int row = r0+tid;
    int tg = tgt[(row&31)*NS + (row>>5)];
    t1c[tid] = (tg >= C1V && tg < C2V) ? (tg - C1V) : -1;
  }
  int mt = wave&1, nt = wave>>1;
  float exr[4] = {0.f,0.f,0.f,0.f};
  for (int ch = 0; ch < 30; ch++){
    int cc0 = (strip*30 + ch)*32;
    __syncthreads();
    #pragma unroll
    for (int it = 0; it < 4; it++){
      int idx = tid + it*256;
      int wr = idx>>5, h4 = idx&31;
      int col = cc0 + wr; if (col >= CSZ1V) col = 0;
      float4 v = *(const float4*)(w2 + (size_t)col*128 + h4*4);
      *(unsigned long long*)(wt + wr*272 + h4*8) = pk4(v);
    }
    __syncthreads();
    f32x4 acc = chainT(pt + mt*16*272, wt + nt*16*272, 272, 272, 4, lane);
    int g = cc0 + nt*16 + lr;
    if (g < CSZ1V){
      #pragma unroll
      for (int r2=0;r2<4;r2++){
        int row = mt*16 + lq*4 + r2;
        float v = acc[r2];
        exr[r2] += __expf(v);
        if (g == t1c[row]) l1p[r0+row] = v;
      }
    }
  }
  #pragma unroll
  for (int r2=0;r2<4;r2++){
    float e = exr[r2];
    e += __shfl_xor(e,1); e += __shfl_xor(e,2); e += __shfl_xor(e,4); e += __shfl_xor(e,8);
    if (lr == 0) atomicAdd(&sums[2048 + r0 + mt*16 + lq*4 + r2], e);
  }
}

// TAIL2: logits = P2(2048x32) @ t2w2.T(32x40000). Grid (64, 8); strip = 40 chunks x 128 cols.
__global__ __launch_bounds__(256) void kt2M(const float* __restrict__ P2,
                                            const float* __restrict__ w2,
                                            const int* __restrict__ tgt,
                                            float* __restrict__ sums, float* __restrict__ l2p){
  __shared__ __align__(16) char pt[32*80];
  __shared__ __align__(16) char wt[128*80];
  __shared__ int t2c[32];
  int r0 = blockIdx.x*32, tid = threadIdx.x;
  int strip = blockIdx.y;
  int lane = tid&63, wave = tid>>6;
  int lr = lane&15, lq = lane>>4;
  {
    int idx = tid;
    if (idx < 32*8){
      int rl = idx>>3, h4 = idx&7;
      float4 v = *(const float4*)(P2 + (size_t)(r0+rl)*32 + h4*4);
      *(unsigned long long*)(pt + rl*80 + h4*8) = pk4(v);
    }
  }
  if (tid < 32){
    int row = r0+tid;
    int tg = tgt[(row&31)*NS + (row>>5)];
    t2c[tid] = (tg >= C2V) ? (tg - C2V) : -1;
  }
  int mt = wave&1, ctb = wave>>1;   // this wave's col tiles: ctb, ctb+2, ctb+4, ctb+6
  float exr[4] = {0.f,0.f,0.f,0.f};
  for (int ch = 0; ch < 40; ch++){
    int cc0 = (strip*40 + ch)*128;
    __syncthreads();
    #pragma unroll
    for (int it = 0; it < 4; it++){
      int idx = tid + it*256;
      int wr = idx>>3, h4 = idx&7;
      int col = cc0 + wr; if (col >= CSZ2V) col = 0;
      float4 v = *(const float4*)(w2 + (size_t)col*32 + h4*4);
      *(unsigned long long*)(wt + wr*80 + h4*8) = pk4(v);
    }
    __syncthreads();
    #pragma unroll
    for (int j = 0; j < 4; j++){
      int ct = ctb + j*2;
      f32x4 acc = chainT(pt + mt*16*80, wt + ct*16*80, 80, 80, 1, lane);
      int g = cc0 + ct*16 + lr;
      if (g < CSZ2V){
        #pragma unroll
        for (int r2=0;r2<4;r2++){
          int row = mt*16 + lq*4 + r2;
          float v = acc[r2];
          exr[r2] += __expf(v);
          if (g == t2c[row]) l2p[r0+row] = v;
        }
      }
    }
  }
  #pragma unroll
  for (int r2=0;r2<4;r2++){
    float e = exr[r2];
    e += __shfl_xor(e,1); e += __shfl_xor(e,2); e += __shfl_xor(e,4); e += __shfl_xor(e,8);
    if (lr == 0) atomicAdd(&sums[4096 + r0 + mt*16 + lq*4 + r2], e);
  }
}

// ================= final gather =================

__global__ __launch_bounds__(256) void kfinal(const float* __restrict__ sums,
                                              const float* __restrict__ hlt, const float* __restrict__ hc1,
                                              const float* __restrict__ hc2, const float* __restrict__ l1p,
                                              const float* __restrict__ l2p, const int* __restrict__ tgt,
                                              float* __restrict__ out){
  __shared__ float red[256];
  int tid = threadIdx.x;
  float acc = 0.f;
  for (int n = tid; n < 2048; n += 256){
    int s = n >> 5, b = n & 31;
    int tg = tgt[b*NS + s];
    float lsh = logf(sums[n]);
    float v;
    if (tg < C1V) v = hlt[n] - lsh;
    else if (tg < C2V) v = (hc1[n] - lsh) + (l1p[n] - logf(sums[2048+n]));
    else v = (hc2[n] - lsh) + (l2p[n] - logf(sums[4096+n]));
    out[O_LP + n] = v;
    acc += v;
  }
  red[tid] = acc;
  __syncthreads();
  for (int off=128; off>0; off>>=1){ if (tid<off) red[tid] += red[tid+off]; __syncthreads(); }
  if (tid==0) out[O_LOSS] = -red[0] / 2048.0f;
}

extern "C" void kernel_launch(void* const* d_in, const int* in_sizes, int n_in,
                              void* d_out, int out_size, void* d_ws, size_t ws_size,
                              hipStream_t stream){
  (void)in_sizes; (void)n_in; (void)out_size; (void)ws_size;
  ScanArgs sa;
  sa.inputs = (const int*)d_in[0];
  sa.topics = (const int*)d_in[1];
  sa.out0   = (const float*)d_in[2];
  sa.h0in   = (const float*)d_in[3];
  sa.c0in   = (const float*)d_in[4];
  sa.mask   = (const float*)d_in[5];
  sa.cover  = (const float*)d_in[7];
  sa.emb    = (const float*)d_in[8];
  sa.Uf     = (const float*)d_in[9];
  sa.Ua     = (const float*)d_in[10];
  sa.Wa     = (const float*)d_in[11];
  sa.vaw    = (const float*)d_in[12];
  sa.vab    = (const float*)d_in[13];
  sa.wih0   = (const float*)d_in[14];
  sa.whh0   = (const float*)d_in[15];
  sa.bih0   = (const float*)d_in[16];
  sa.bhh0   = (const float*)d_in[17];
  sa.wih1   = (const float*)d_in[18];
  sa.whh1   = (const float*)d_in[19];
  sa.bih1   = (const float*)d_in[20];
  sa.bhh1   = (const float*)d_in[21];
  sa.ws  = (char*)d_ws;
  sa.out = (float*)d_out;

  char* wsb = (char*)d_ws;
  const int* target = (const int*)d_in[6];
  float* outf = (float*)d_out;

  hipMemsetAsync(wsb + SUMS_B, 0, 6144*sizeof(float), stream);
  hipMemsetAsync(wsb + BAR_B, 0, 16384, stream);   // preamble barrier flags + go
  hipMemsetAsync(wsb + CTR_B, 0, 12288, stream);   // scan-loop counters (A/C/D)

  static int lds_set = 0;
  if (!lds_set){
    hipFuncSetAttribute((const void*)scan_kernel,
                        hipFuncAttributeMaxDynamicSharedMemorySize, LDS_BYTES);
    hipFuncSetAttribute((const void*)kheadM,
                        hipFuncAttributeMaxDynamicSharedMemorySize, 66816);
    lds_set = 1;
  }

  void* args[] = { (void*)&sa };
  hipLaunchCooperativeKernel((void*)scan_kernel, dim3(208), dim3(256), args, LDS_BYTES, stream);

  const float* X = outf + O_OUTS;
  kproj<<<dim3(128,2),dim3(256),0,stream>>>(X, (const float*)d_in[23], (const float*)d_in[25],
                                            (float*)(wsb+P1_B), (float*)(wsb+P2_B));
  kheadM<<<dim3(64,8),dim3(256),66816,stream>>>(X, (const float*)d_in[22], target,
           (float*)(wsb+SUMS_B), (float*)(wsb+HLT_B), (float*)(wsb+HC1_B), (float*)(wsb+HC2_B));
  kt1M<<<dim3(64,8),dim3(256),0,stream>>>((const float*)(wsb+P1_B), (const float*)d_in[24], target,
           (float*)(wsb+SUMS_B), (float*)(wsb+L1P_B));
  kt2M<<<dim3(64,8),dim3(256),0,stream>>>((const float*)(wsb+P2_B), (const float*)d_in[26], target,
           (float*)(wsb+SUMS_B), (float*)(wsb+L2P_B));
  kfinal<<<dim3(1),dim3(256),0,stream>>>((const float*)(wsb+SUMS_B),
           (const float*)(wsb+HLT_B), (const float*)(wsb+HC1_B), (const float*)(wsb+HC2_B),
           (const float*)(wsb+L1P_B), (const float*)(wsb+L2P_B), target, outf);
}

// Round 9
// 2963.338 us; speedup vs baseline: 1.0683x; 1.0683x over previous
//
#include <hip/hip_runtime.h>
#include <cmath>

typedef __attribute__((ext_vector_type(8))) short short8;
typedef __attribute__((ext_vector_type(4))) float f32x4;

#define NB 32
#define NS 64
#define NK 5
#define NE 512
#define NH 512
#define C1V 2500
#define C2V 10000
#define CSZ1V 7500
#define CSZ2V 40000

// ---- workspace BYTE offsets ----
#define PWR_B   0u          // 4*512*512 f32 = 4MB (preamble only; aliased by ghE)
#define GHE_B   0u          // 64*2048*32 bf16 = 8MB
#define QB_B    8388608u    // 32*512 bf16
#define H1B_B   8421376u
#define H0B_B   8454144u
#define PHI_B   8488192u    // 160 f32
#define P1_B    8488832u    // 2048*128 f32
#define P2_B    9537408u    // 2048*32 f32
#define SUMS_B  9799552u    // 3*2048 f32
#define HLT_B   9824128u
#define HC1_B   9832320u
#define HC2_B   9840512u
#define L1P_B   9848704u
#define L2P_B   9856896u
#define BAR_B   9865216u    // preamble flags 208*64B = 13312, go at +13312; memset 16384
#define SB2_B   9881600u    // 80*32 f32 score partials; end 9,891,840
#define SFLG_B  9891840u    // PACKED scan flags: A[0..79] u32 @+0, C[0..127] @+512, D[0..127] @+1024; 1536B

// ---- d_out float offsets (verified) ----
#define O_LP   0
#define O_LOSS 2048
#define O_OUTS 2049
#define O_HF   1050625
#define O_CF   1083393
#define O_ATTN 1116161
#define O_COVF 1126401

// ---- LDS byte offsets (scan kernel) ----
#define ROWB 1040           // 520 bf16 per padded row (mult of 16 for b128 loads)
#define L_W1  0
#define L_WI  16640
#define L_W0  33280
#define L_ACT 49920
#define L_TP  83200
#define L_GH1 93440
#define L_GH0 95488
#define L_GB  97536
#define L_AL  99584
#define LDS_BYTES 100352
#define A_MI  0
#define A_ACT 33280
#define A_SCR 66560

__device__ __forceinline__ float sigmf(float x){ return 1.0f/(1.0f + expf(-x)); }

__device__ __forceinline__ unsigned short f2b16(float f){
  unsigned u = __float_as_uint(f);
  return (unsigned short)((u + 0x7fffu + ((u>>16)&1u)) >> 16);
}
__device__ __forceinline__ float b2f16(unsigned short s){ return __uint_as_float(((unsigned)s)<<16); }

// pack 4 f32 -> 4 bf16 in a u64
__device__ __forceinline__ unsigned long long pk4(float4 v){
  unsigned long long u = (unsigned long long)f2b16(v.x)
    | ((unsigned long long)f2b16(v.y) << 16)
    | ((unsigned long long)f2b16(v.z) << 32)
    | ((unsigned long long)f2b16(v.w) << 48);
  return u;
}

// ---- agent-scope (coherence-point) primitives ----
__device__ __forceinline__ unsigned ldf(unsigned* p){
  return __hip_atomic_load(p, __ATOMIC_RELAXED, __HIP_MEMORY_SCOPE_AGENT);
}
__device__ __forceinline__ void stf(unsigned* p, unsigned v){
  __hip_atomic_store(p, v, __ATOMIC_RELAXED, __HIP_MEMORY_SCOPE_AGENT);
}
__device__ __forceinline__ void sta64(unsigned long long* p, unsigned long long v){
  __hip_atomic_store(p, v, __ATOMIC_RELAXED, __HIP_MEMORY_SCOPE_AGENT);
}
__device__ __forceinline__ unsigned long long lda64(const unsigned long long* p){
  return __hip_atomic_load((unsigned long long*)p, __ATOMIC_RELAXED, __HIP_MEMORY_SCOPE_AGENT);
}
__device__ __forceinline__ void staf(float* p, float v){
  __hip_atomic_store(p, v, __ATOMIC_RELAXED, __HIP_MEMORY_SCOPE_AGENT);
}
__device__ __forceinline__ float ldaf(const float* p){
  return __hip_atomic_load((float*)p, __ATOMIC_RELAXED, __HIP_MEMORY_SCOPE_AGENT);
}

// ---- heavy barrier (preamble only) ----
__device__ __forceinline__ void bar_arrive(unsigned* flags, int wg, unsigned gen, int tid){
  __syncthreads();
  if (tid == 0){
    __threadfence();
    stf(flags + wg*16, gen);
  }
}
__device__ __forceinline__ void bar_collect(unsigned* flags, unsigned* go, unsigned gen,
                                            int first, int cnt, int tid){
  for (int i = tid; i < cnt; i += 256){
    unsigned* f = flags + (first + i)*16;
    while (ldf(f) < gen) __builtin_amdgcn_s_sleep(1);
  }
  __syncthreads();
  if (tid == 0) stf(go, gen);
}
__device__ __forceinline__ void bar_wait(unsigned* go, unsigned gen, int tid){
  if (tid == 0){
    while (ldf(go) < gen) __builtin_amdgcn_s_sleep(1);
    __threadfence();
  }
  __syncthreads();
}

// ---- scan-loop sync: packed parallel flags, narrow pollers ----
// Producers: independent plain agent stores to PACKED u32 flags (no RMW, parallel).
// Consumers: 16 threads poll u64 PAIRS (2 flags/load, 8 lines per 128 flags) with
// backoff — ~16x less read traffic than 128-thread/128-line polling, same 1-hop.
__device__ __forceinline__ void waitp(unsigned long long* F, int npair, unsigned gen, int tid){
  if (tid < 16){
    for (int p = tid; p < npair; p += 16){
      for (;;){
        unsigned long long v = lda64(F + p);
        if ((unsigned)v >= gen && (unsigned)(v >> 32) >= gen) break;
        __builtin_amdgcn_s_sleep(2);
      }
    }
  }
  __syncthreads();
}

// D[m][n] += A[m][k]*B[n][k] over K=512, one 16x16 tile, rows padded ROWB.
__device__ __forceinline__ f32x4 chain16(const char* Abase, const char* Bbase, int lane){
  f32x4 acc = {0.f,0.f,0.f,0.f};
  int lr = lane & 15, lq = lane >> 4;
  const char* ap = Abase + lr*ROWB + lq*16;
  const char* bp = Bbase + lr*ROWB + lq*16;
  #pragma unroll
  for (int ks=0; ks<16; ks++){
    short8 af = *(const short8*)(ap + ks*64);
    short8 bf = *(const short8*)(bp + ks*64);
    acc = __builtin_amdgcn_mfma_f32_16x16x32_bf16(af, bf, acc, 0, 0, 0);
  }
  return acc;
}

// generic-stride, generic-K chain: K = nks*32. strides must be multiples of 16B.
__device__ __forceinline__ f32x4 chainT(const char* Abase, const char* Bbase,
                                        int sA, int sB, int nks, int lane){
  f32x4 acc = {0.f,0.f,0.f,0.f};
  int lr = lane & 15, lq = lane >> 4;
  const char* ap = Abase + lr*sA + lq*16;
  const char* bp = Bbase + lr*sB + lq*16;
  for (int ks=0; ks<nks; ks++){
    short8 af = *(const short8*)(ap + ks*64);
    short8 bf = *(const short8*)(bp + ks*64);
    acc = __builtin_amdgcn_mfma_f32_16x16x32_bf16(af, bf, acc, 0, 0, 0);
  }
  return acc;
}

__device__ __forceinline__ void stage32(const unsigned short* g, char* dst, int tid){
  int b = tid & 31, seg = tid >> 5;
  const float4* s4 = (const float4*)(g + (size_t)b*512 + seg*64);
  float4* d4 = (float4*)(dst + b*ROWB + seg*128);
  #pragma unroll
  for (int i=0;i<8;i++) d4[i] = s4[i];
}

// agent-scope variant used inside the scan loop
__device__ __forceinline__ void stage32a(const unsigned short* g, char* dst, int tid){
  int b = tid & 31, seg = tid >> 5;
  const unsigned long long* s8 = (const unsigned long long*)(g + (size_t)b*512 + seg*64);
  unsigned long long* d8 = (unsigned long long*)(dst + b*ROWB + seg*128);
  #pragma unroll
  for (int i=0;i<16;i++) d8[i] = lda64(s8 + i);
}

__device__ __forceinline__ float dot512(const float* __restrict__ x, const float* __restrict__ w){
  const float4* x4 = (const float4*)x;
  const float4* w4 = (const float4*)w;
  float a0=0.f,a1=0.f,a2=0.f,a3=0.f;
  #pragma unroll 8
  for (int h=0; h<128; h++){
    float4 xx = x4[h]; float4 ww = w4[h];
    a0 = fmaf(xx.x, ww.x, a0); a1 = fmaf(xx.y, ww.y, a1);
    a2 = fmaf(xx.z, ww.z, a2); a3 = fmaf(xx.w, ww.w, a3);
  }
  return (a0+a1)+(a2+a3);
}

struct ScanArgs {
  const int* inputs; const int* topics; const float* out0;
  const float* h0in; const float* c0in; const float* mask; const float* cover;
  const float* emb; const float* Uf; const float* Ua; const float* Wa;
  const float* vaw; const float* vab;
  const float* wih0; const float* whh0; const float* bih0; const float* bhh0;
  const float* wih1; const float* whh1; const float* bih1; const float* bhh1;
  char* ws; float* out;
};

// ====================== scan kernel (round-6 structure; packed flags) ======================
// 208 wgs x 256 threads. wgs 0..79 attention (wg0 = preamble collector), 80..207 LSTM.
__global__ __launch_bounds__(256) void scan_kernel(ScanArgs a){
  extern __shared__ char sm[];
  const int wg = blockIdx.x, tid = threadIdx.x;
  const int lane = tid & 63, wave = tid >> 6;
  const int GT = gridDim.x * blockDim.x;
  const int gt = wg*256 + tid;
  char* wsb = a.ws;
  unsigned* bflags = (unsigned*)(wsb + BAR_B);
  unsigned* bgo    = (unsigned*)(wsb + BAR_B + 13312);
  unsigned* SFA    = (unsigned*)(wsb + SFLG_B);
  unsigned* SFC    = (unsigned*)(wsb + SFLG_B + 512);
  unsigned* SFD    = (unsigned*)(wsb + SFLG_B + 1024);
  const bool isAttn = (wg < 80);
  const int head = wg >> 4;
  const int e0 = (wg & 15) * 32;
  const int lw = wg - 80;
  const int u0 = lw * 4;

  f32x4 pkr = {0.f,0.f,0.f,0.f};
  float var[4] = {0.f,0.f,0.f,0.f};
  float b0r[4] = {0,0,0,0}, b1r[4] = {0,0,0,0};
  float c0r = 0.f, c1r = 0.f;
  float covr[NK] = {0,0,0,0,0}, phir[NK] = {1,1,1,1,1};

  // ================= P0a: inits + phi =================
  {
    unsigned short* qb  = (unsigned short*)(wsb + QB_B);
    unsigned short* h1b = (unsigned short*)(wsb + H1B_B);
    unsigned short* h0b = (unsigned short*)(wsb + H0B_B);
    for (int i = gt; i < NB*NH; i += GT){
      qb[i]  = f2b16(a.out0[i]);
      h1b[i] = f2b16(a.h0in[NB*NH + i]);
      h0b[i] = f2b16(a.h0in[i]);
    }
    if (gt < 160){
      int b = gt/NK, k = gt%NK;
      float ms = 0.f; for (int s=0;s<NS;s++) ms += a.mask[b*NS+s];
      float acc = 0.f;
      for (int kk=0; kk<NK; kk++){
        const float* te = a.emb + (size_t)a.topics[b*NK+kk]*NE;
        const float* uf = a.Uf + (size_t)k*(NK*NE) + kk*NE;
        acc += dot512(te, uf);
      }
      ((float*)(wsb + PHI_B))[gt] = ms * sigmf(acc);
    }
  }
  bar_arrive(bflags, wg, 1, tid);
  if (wg==0) bar_collect(bflags, bgo, 1, 0, 208, tid);
  bar_wait(bgo, 1, tid);

  // ================= P1: Wa powers (fp32) =================
  for (int r=0; r<4; r++){
    const float* Asrc = (r==0) ? a.Wa : (const float*)(wsb + PWR_B) + (size_t)(r-1)*NH*NH;
    float* Mo = (float*)(wsb + PWR_B) + (size_t)r*NH*NH;
    for (int d = gt; d < NH*NH; d += GT){
      int row = d >> 9, col = d & 511;
      const float* ar = Asrc + (size_t)row*NH;
      float acc = 0.f;
      for (int k2=0;k2<NH;k2++) acc = fmaf(ar[k2], a.Wa[(size_t)k2*NH + col], acc);
      Mo[d] = acc;
    }
    unsigned g = 2 + r;
    bar_arrive(bflags, wg, g, tid);
    if (wg==0) bar_collect(bflags, bgo, g, 0, 208, tid);
    bar_wait(bgo, g, tid);
  }

  // ================= P2: attn pk+Mi; lstm tp =================
  if (isAttn){
    for (int idx=tid; idx<32*512; idx+=256){
      int r = idx>>9, k = idx&511;
      *(unsigned short*)(sm + A_MI + r*ROWB + k*2) = f2b16(a.Ua[(size_t)(e0+r)*NE + k]);
    }
    for (int idx=tid; idx<32*512; idx+=256){
      int r = idx>>9, k = idx&511;
      int tok = a.topics[r*NK + head];
      *(unsigned short*)(sm + A_ACT + r*ROWB + k*2) = f2b16(a.emb[(size_t)tok*NE + k]);
    }
    __syncthreads();
    {
      int mt = wave&1, nt = wave>>1;
      pkr = chain16(sm + A_MI + mt*16*ROWB, sm + A_ACT + nt*16*ROWB, lane);
      int lq = lane>>4;
      #pragma unroll
      for (int r2=0;r2<4;r2++) var[r2] = a.vaw[e0 + mt*16 + lq*4 + r2];
    }
    __syncthreads();
    const float* Msrc = (head==0) ? a.Wa : (const float*)(wsb + PWR_B) + (size_t)(head-1)*NH*NH;
    for (int idx=tid; idx<32*512; idx+=256){
      int r = idx>>9, k = idx&511;
      *(unsigned short*)(sm + A_MI + r*ROWB + k*2) = f2b16(Msrc[(size_t)(e0+r)*NH + k]);
    }
  } else {
    for (int idx=tid; idx<16*512; idx+=256){
      int rr = idx>>9, k = idx&511;
      int j = (rr>>2)*NH + u0 + (rr&3);
      *(unsigned short*)(sm + L_WI + rr*ROWB + k*2) = f2b16(a.wih0[(size_t)j*(2*NE) + NE + k]);
    }
    __syncthreads();
    for (int rnd=0; rnd<5; rnd++){
      for (int idx=tid; idx<32*512; idx+=256){
        int r = idx>>9, k = idx&511;
        int tok = a.topics[rnd*32 + r];
        *(unsigned short*)(sm + L_ACT + r*ROWB + k*2) = f2b16(a.emb[(size_t)tok*NE + k]);
      }
      __syncthreads();
      if (wave < 2){
        f32x4 acc = chain16(sm + L_ACT + wave*16*ROWB, sm + L_WI, lane);
        int lr = lane&15, lq = lane>>4;
        #pragma unroll
        for (int r2=0;r2<4;r2++){
          int row = rnd*32 + wave*16 + lq*4 + r2;
          int bb = row/5, kk = row - bb*5;
          *(float*)(sm + L_TP + (((kk*16) + lr)*32 + bb)*4) = acc[r2];
        }
      }
      __syncthreads();
    }
  }
  // g6: attn done reading powers -> lstm may overwrite with ghE
  bar_arrive(bflags, wg, 6, tid);
  if (wg==0) bar_collect(bflags, bgo, 6, 0, 208, tid);
  if (!isAttn) bar_wait(bgo, 6, tid);

  // ================= P4 (lstm only): ghE + weights + regs + gh0 init =================
  if (!isAttn){
    for (int idx=tid; idx<16*512; idx+=256){
      int rr = idx>>9, k = idx&511;
      int j = (rr>>2)*NH + u0 + (rr&3);
      *(unsigned short*)(sm + 66560 + rr*ROWB + k*2) = f2b16(a.wih0[(size_t)j*(2*NE) + k]);
    }
    __syncthreads();
    unsigned short* gE = (unsigned short*)(wsb + GHE_B);
    for (int it=0; it<32; it++){
      for (int idx=tid; idx<64*512; idx+=256){
        int r = idx>>9, k = idx&511;
        int grow = it*64 + r;
        int tt = grow>>5, bb = grow&31;
        int tok = a.inputs[bb*NS + tt];
        *(unsigned short*)(sm + r*ROWB + k*2) = f2b16(a.emb[(size_t)tok*NE + k]);
      }
      __syncthreads();
      {
        f32x4 acc = chain16(sm + wave*16*ROWB, sm + 66560, lane);
        int lr = lane&15, lq = lane>>4;
        #pragma unroll
        for (int r2=0;r2<4;r2++){
          int grow = it*64 + wave*16 + lq*4 + r2;
          int tt = grow>>5, bb = grow&31;
          int jg = (lr>>2)*NH + u0 + (lr&3);
          gE[((size_t)tt*2048 + jg)*32 + bb] = f2b16(acc[r2]);
        }
      }
      __syncthreads();
    }
    for (int idx=tid; idx<16*512; idx+=256){
      int rr = idx>>9, k = idx&511;
      int j = (rr>>2)*NH + u0 + (rr&3);
      *(unsigned short*)(sm + L_W1 + rr*ROWB + k*2) = f2b16(a.whh1[(size_t)j*NH + k]);
      *(unsigned short*)(sm + L_WI + rr*ROWB + k*2) = f2b16(a.wih1[(size_t)j*NH + k]);
      *(unsigned short*)(sm + L_W0 + rr*ROWB + k*2) = f2b16(a.whh0[(size_t)j*NH + k]);
    }
    if (tid < 128){
      int bb = tid&31, ur = tid>>5;
      #pragma unroll
      for (int g=0; g<4; g++){
        int j = g*NH + u0 + ur;
        b0r[g] = a.bih0[j] + a.bhh0[j];
        b1r[g] = a.bih1[j] + a.bhh1[j];
      }
      c0r = a.c0in[(size_t)bb*NH + u0 + ur];
      c1r = a.c0in[(size_t)NB*NH + bb*NH + u0 + ur];
    }
    if (tid < 32){
      const float* phiG = (const float*)(wsb + PHI_B);
      #pragma unroll
      for (int k=0;k<NK;k++){ covr[k] = a.cover[tid*NK + k]; phir[k] = phiG[tid*NK + k]; }
    }
    __syncthreads();
    stage32((const unsigned short*)(wsb + H0B_B), sm + L_ACT, tid);
    __syncthreads();
    if (wave & 1){
      int nt = wave>>1;
      f32x4 acc = chain16(sm + L_W0, sm + L_ACT + nt*16*ROWB, lane);
      int lr = lane&15, lq = lane>>4;
      #pragma unroll
      for (int r2=0;r2<4;r2++)
        *(float*)(sm + L_GH0 + ((lq*4+r2)*32 + nt*16 + lr)*4) = acc[r2];
    }
    __syncthreads();
  }

  // ================= scan: packed-flag walls (ordering proof == round-6) =================
  for (int t=0; t<NS; t++){
    unsigned gT = (unsigned)t, gT1 = (unsigned)(t+1);
    if (isAttn){
      waitp((unsigned long long*)SFD, 64, gT, tid);   // h1(t-1) fully published
      stage32a((const unsigned short*)(wsb + QB_B), sm + A_ACT, tid);
      __syncthreads();
      int mt = wave&1, nt = wave>>1;
      f32x4 acc = chain16(sm + A_MI + mt*16*ROWB, sm + A_ACT + nt*16*ROWB, lane);
      float v = 0.f;
      #pragma unroll
      for (int r2=0;r2<4;r2++) v += tanhf(acc[r2] + pkr[r2]) * var[r2];
      v += __shfl_xor(v, 16);
      v += __shfl_xor(v, 32);
      if ((lane>>4)==0) *(float*)(sm + A_SCR + (wave*16 + (lane&15))*4) = v;
      __syncthreads();
      if (tid < 32){
        int nt2 = tid>>4, bh = tid&15;
        float s = *(const float*)(sm + A_SCR + ((nt2*2)*16 + bh)*4)
                + *(const float*)(sm + A_SCR + ((nt2*2+1)*16 + bh)*4);
        staf(((float*)(wsb + SB2_B)) + wg*32 + tid, s);
      }
      __syncthreads();                                // drains agent stores
      if (tid == 0) stf(SFA + wg, gT1);               // publish scores(t)
    } else {
      waitp((unsigned long long*)SFD, 64, gT, tid);   // h1(t-1) fully published
      stage32a((const unsigned short*)(wsb + H1B_B), sm + L_ACT, tid);
      __syncthreads();
      if (wave < 2){
        f32x4 acc = chain16(sm + L_W1, sm + L_ACT + wave*16*ROWB, lane);
        int lr = lane&15, lq = lane>>4;
        #pragma unroll
        for (int r2=0;r2<4;r2++)
          *(float*)(sm + L_GH1 + ((lq*4+r2)*32 + wave*16 + lr)*4) = acc[r2];
      }
      waitp((unsigned long long*)SFA, 40, gT1, tid);  // scores(t) ready

      // ---- Phase C ----
      if (tid < 160){
        int k = tid>>5, b = tid&31;
        const float* sb2 = (const float*)(wsb + SB2_B);
        float s = 0.f;
        #pragma unroll
        for (int es=0; es<16; es++) s += ldaf(sb2 + (k*16+es)*32 + b);
        *(float*)(sm + L_GB + tid*4) = s;
      }
      __syncthreads();
      if (tid < 32){
        float vb = a.vab[0];
        float sc[NK], mx = -1e30f;
        #pragma unroll
        for (int k=0;k<NK;k++){
          float s = (*(const float*)(sm + L_GB + (k*32+tid)*4) + vb) * covr[k];
          sc[k] = s; mx = fmaxf(mx, s);
        }
        float sum = 0.f;
        #pragma unroll
        for (int k=0;k<NK;k++){ sc[k] = expf(sc[k]-mx); sum += sc[k]; }
        float inv = 1.0f/sum;
        #pragma unroll
        for (int k=0;k<NK;k++){
          float al = sc[k]*inv;
          *(float*)(sm + L_AL + (tid*NK+k)*4) = al;
          covr[k] = covr[k] - al/phir[k];
          if (lw == 0){
            a.out[O_ATTN + (size_t)(t*NB + tid)*NK + k] = al;
            if (t == NS-1) a.out[O_COVF + tid*NK + k] = covr[k];
          }
        }
      }
      __syncthreads();
      if (tid < 128){
        int bb = tid&31, ur = tid>>5;
        const unsigned short* gE = (const unsigned short*)(wsb + GHE_B);
        float al[NK];
        #pragma unroll
        for (int k=0;k<NK;k++) al[k] = *(const float*)(sm + L_AL + (bb*NK+k)*4);
        float g4[4];
        #pragma unroll
        for (int g=0; g<4; g++){
          int rr = g*4 + ur;
          float x = b2f16(gE[((size_t)t*2048 + g*NH + u0 + ur)*32 + bb]);
          x += *(const float*)(sm + L_GH0 + (rr*32 + bb)*4);
          x += b0r[g];
          #pragma unroll
          for (int k=0;k<NK;k++) x += al[k] * *(const float*)(sm + L_TP + ((k*16+rr)*32 + bb)*4);
          g4[g] = x;
        }
        float cn = sigmf(g4[1])*c0r + sigmf(g4[0])*tanhf(g4[2]);
        float hn = sigmf(g4[3])*tanhf(cn);
        c0r = cn;
        ((unsigned short*)(sm + L_ACT))[bb*4 + ur] = f2b16(hn);
        if (t == NS-1){
          a.out[O_HF + (size_t)bb*NH + u0 + ur] = hn;
          a.out[O_CF + (size_t)bb*NH + u0 + ur] = cn;
        }
      }
      __syncthreads();
      if (tid < 32){
        unsigned long long v = *(const unsigned long long*)((const unsigned short*)(sm + L_ACT) + tid*4);
        sta64((unsigned long long*)((unsigned short*)(wsb + H0B_B) + (size_t)tid*NH + u0), v);
      }
      __syncthreads();                                // drains agent stores
      if (tid == 0) stf(SFC + lw, gT1);               // publish h0 slice(t)
      waitp((unsigned long long*)SFC, 64, gT1, tid);  // h0(t) fully published

      // ---- Phase D ----
      stage32a((const unsigned short*)(wsb + H0B_B), sm + L_ACT, tid);
      __syncthreads();
      {
        int mat = wave&1, nt = wave>>1;
        f32x4 acc = chain16(sm + (mat ? L_W0 : L_WI), sm + L_ACT + nt*16*ROWB, lane);
        int lr = lane&15, lq = lane>>4;
        char* dst = sm + (mat ? L_GH0 : L_GB);
        #pragma unroll
        for (int r2=0;r2<4;r2++)
          *(float*)(dst + ((lq*4+r2)*32 + nt*16 + lr)*4) = acc[r2];
      }
      __syncthreads();
      if (tid < 128){
        int bb = tid&31, ur = tid>>5;
        float g4[4];
        #pragma unroll
        for (int g=0; g<4; g++){
          int rr = g*4+ur;
          g4[g] = *(const float*)(sm + L_GB + (rr*32+bb)*4)
                + *(const float*)(sm + L_GH1 + (rr*32+bb)*4) + b1r[g];
        }
        float cn = sigmf(g4[1])*c1r + sigmf(g4[0])*tanhf(g4[2]);
        float hn = sigmf(g4[3])*tanhf(cn);
        c1r = cn;
        ((unsigned short*)(sm + L_ACT))[bb*4 + ur] = f2b16(hn);
        a.out[O_OUTS + (size_t)(t*NB + bb)*NH + u0 + ur] = hn;
        if (t == NS-1){
          a.out[O_HF + (size_t)(NB + bb)*NH + u0 + ur] = hn;
          a.out[O_CF + (size_t)(NB + bb)*NH + u0 + ur] = cn;
        }
      }
      __syncthreads();
      if (tid < 32){
        unsigned long long v = *(const unsigned long long*)((const unsigned short*)(sm + L_ACT) + tid*4);
        sta64((unsigned long long*)((unsigned short*)(wsb + QB_B)  + (size_t)tid*NH + u0), v);
        sta64((unsigned long long*)((unsigned short*)(wsb + H1B_B) + (size_t)tid*NH + u0), v);
      }
      __syncthreads();                                // drains agent stores
      if (tid == 0) stf(SFD + lw, gT1);               // publish h1 slice(t)
    }
  }
}

// ================= adaptive log-softmax tail: MFMA GEMMs, column-split for TLP =================

// P1 = X @ t1w1.T, P2 = X @ t2w1.T  (round-1 kernel + y-split for occupancy)
__global__ __launch_bounds__(256) void kproj(const float* __restrict__ X,
                                             const float* __restrict__ t1w1,
                                             const float* __restrict__ t2w1,
                                             float* __restrict__ P1, float* __restrict__ P2){
  __shared__ float xs[16*516];
  int r0 = blockIdx.x*16, tid = threadIdx.x;
  int yy = blockIdx.y;
  for (int idx=tid; idx<16*512; idx+=256){ int rl=idx>>9, h=idx&511; xs[rl*516+h] = X[(size_t)(r0+rl)*NH + h]; }
  __syncthreads();
  if (yy == 0){
    for (int k=0;k<4;k++){
      int d = tid + 256*k; int rl = d & 15, c = d >> 4;
      P1[(size_t)(r0+rl)*128 + c] = dot512(xs + rl*516, t1w1 + (size_t)c*NH);
    }
  } else {
    for (int k=4;k<8;k++){
      int d = tid + 256*k; int rl = d & 15, c = d >> 4;
      P1[(size_t)(r0+rl)*128 + c] = dot512(xs + rl*516, t1w1 + (size_t)c*NH);
    }
    for (int k=0;k<2;k++){
      int d = tid + 256*k; int rl = d & 15, c = d >> 4;
      P2[(size_t)(r0+rl)*32 + c] = dot512(xs + rl*516, t2w1 + (size_t)c*NH);
    }
  }
}

// HEAD: logits = X(2048x512) @ hw.T(512x2502). Grid (64 row-blocks, 8 col-strips).
// Strip = 10 chunks x 32 cols (8*10*32 = 2560 >= 2504).
__global__ __launch_bounds__(256) void kheadM(const float* __restrict__ X,
                                              const float* __restrict__ hw,
                                              const int* __restrict__ tgt,
                                              float* __restrict__ sums,
                                              float* __restrict__ hlt, float* __restrict__ hc1,
                                              float* __restrict__ hc2){
  extern __shared__ char sm[];
  int* caps = (int*)(sm + 66560);
  int r0 = blockIdx.x*32, tid = threadIdx.x;
  int strip = blockIdx.y;
  int lane = tid&63, wave = tid>>6;
  int lr = lane&15, lq = lane>>4;
  // stage X rows (f32 -> bf16), vectorized
  #pragma unroll
  for (int it = 0; it < 16; it++){
    int idx = tid + it*256;
    int rl = idx>>7, h4 = idx&127;
    float4 v = *(const float4*)(X + (size_t)(r0+rl)*NH + h4*4);
    *(unsigned long long*)(sm + rl*ROWB + h4*8) = pk4(v);
  }
  if (tid < 32){
    int row = r0+tid;
    int tg = tgt[(row&31)*NS + (row>>5)];
    caps[tid] = tg < C1V ? tg : (C1V-1);
  }
  int mt = wave&1, nt = wave>>1;
  float exr[4] = {0.f,0.f,0.f,0.f};
  for (int ch = 0; ch < 10; ch++){
    int cc0 = (strip*10 + ch)*32;
    __syncthreads();                         // protect WT from previous iteration's readers
    #pragma unroll
    for (int it = 0; it < 16; it++){
      int idx = tid + it*256;
      int wr = idx>>7, h4 = idx&127;
      int col = cc0 + wr; if (col >= C1V+2) col = 0;
      float4 v = *(const float4*)(hw + (size_t)col*NH + h4*4);
      *(unsigned long long*)(sm + 33280 + wr*ROWB + h4*8) = pk4(v);
    }
    __syncthreads();
    f32x4 acc = chain16(sm + mt*16*ROWB, sm + 33280 + nt*16*ROWB, lane);
    int g = cc0 + nt*16 + lr;
    if (g < C1V+2){
      #pragma unroll
      for (int r2=0;r2<4;r2++){
        int row = mt*16 + lq*4 + r2;
        float v = acc[r2];
        exr[r2] += __expf(v);
        if (g == caps[row]) hlt[r0+row] = v;
        else if (g == C1V) hc1[r0+row] = v;
        else if (g == C1V+1) hc2[r0+row] = v;
      }
    }
  }
  #pragma unroll
  for (int r2=0;r2<4;r2++){
    float e = exr[r2];
    e += __shfl_xor(e,1); e += __shfl_xor(e,2); e += __shfl_xor(e,4); e += __shfl_xor(e,8);
    if (lr == 0) atomicAdd(&sums[r0 + mt*16 + lq*4 + r2], e);
  }
}

// TAIL1: logits = P1(2048x128) @ t1w2.T(128x7500). Grid (64, 8); strip = 30 chunks x 32 cols.
__global__ __launch_bounds__(256) void kt1M(const float* __restrict__ P1,
                                            const float* __restrict__ w2,
                                            const int* __restrict__ tgt,
                                            float* __restrict__ sums, float* __restrict__ l1p){
  __shared__ __align__(16) char pt[32*272];
  __shared__ __align__(16) char wt[32*272];
  __shared__ int t1c[32];
  int r0 = blockIdx.x*32, tid = threadIdx.x;
  int strip = blockIdx.y;
  int lane = tid&63, wave = tid>>6;
  int lr = lane&15, lq = lane>>4;
  #pragma unroll
  for (int it = 0; it < 4; it++){
    int idx = tid + it*256;
    int rl = idx>>5, h4 = idx&31;
    float4 v = *(const float4*)(P1 + (size_t)(r0+rl)*128 + h4*4);
    *(unsigned long long*)(pt + rl*272 + h4*8) = pk4(v);
  }
  if (tid < 32){
    int row = r0+tid;
    int tg = tgt[(row&31)*NS + (row>>5)];
    t1c[tid] = (tg >= C1V && tg < C2V) ? (tg - C1V) : -1;
  }
  int mt = wave&1, nt = wave>>1;
  float exr[4] = {0.f,0.f,0.f,0.f};
  for (int ch = 0; ch < 30; ch++){
    int cc0 = (strip*30 + ch)*32;
    __syncthreads();
    #pragma unroll
    for (int it = 0; it < 4; it++){
      int idx = tid + it*256;
      int wr = idx>>5, h4 = idx&31;
      int col = cc0 + wr; if (col >= CSZ1V) col = 0;
      float4 v = *(const float4*)(w2 + (size_t)col*128 + h4*4);
      *(unsigned long long*)(wt + wr*272 + h4*8) = pk4(v);
    }
    __syncthreads();
    f32x4 acc = chainT(pt + mt*16*272, wt + nt*16*272, 272, 272, 4, lane);
    int g = cc0 + nt*16 + lr;
    if (g < CSZ1V){
      #pragma unroll
      for (int r2=0;r2<4;r2++){
        int row = mt*16 + lq*4 + r2;
        float v = acc[r2];
        exr[r2] += __expf(v);
        if (g == t1c[row]) l1p[r0+row] = v;
      }
    }
  }
  #pragma unroll
  for (int r2=0;r2<4;r2++){
    float e = exr[r2];
    e += __shfl_xor(e,1); e += __shfl_xor(e,2); e += __shfl_xor(e,4); e += __shfl_xor(e,8);
    if (lr == 0) atomicAdd(&sums[2048 + r0 + mt*16 + lq*4 + r2], e);
  }
}

// TAIL2: logits = P2(2048x32) @ t2w2.T(32x40000). Grid (64, 8); strip = 40 chunks x 128 cols.
__global__ __launch_bounds__(256) void kt2M(const float* __restrict__ P2,
                                            const float* __restrict__ w2,
                                            const int* __restrict__ tgt,
                                            float* __restrict__ sums, float* __restrict__ l2p){
  __shared__ __align__(16) char pt[32*80];
  __shared__ __align__(16) char wt[128*80];
  __shared__ int t2c[32];
  int r0 = blockIdx.x*32, tid = threadIdx.x;
  int strip = blockIdx.y;
  int lane = tid&63, wave = tid>>6;
  int lr = lane&15, lq = lane>>4;
  {
    int idx = tid;
    if (idx < 32*8){
      int rl = idx>>3, h4 = idx&7;
      float4 v = *(const float4*)(P2 + (size_t)(r0+rl)*32 + h4*4);
      *(unsigned long long*)(pt + rl*80 + h4*8) = pk4(v);
    }
  }
  if (tid < 32){
    int row = r0+tid;
    int tg = tgt[(row&31)*NS + (row>>5)];
    t2c[tid] = (tg >= C2V) ? (tg - C2V) : -1;
  }
  int mt = wave&1, ctb = wave>>1;   // this wave's col tiles: ctb, ctb+2, ctb+4, ctb+6
  float exr[4] = {0.f,0.f,0.f,0.f};
  for (int ch = 0; ch < 40; ch++){
    int cc0 = (strip*40 + ch)*128;
    __syncthreads();
    #pragma unroll
    for (int it = 0; it < 4; it++){
      int idx = tid + it*256;
      int wr = idx>>3, h4 = idx&7;
      int col = cc0 + wr; if (col >= CSZ2V) col = 0;
      float4 v = *(const float4*)(w2 + (size_t)col*32 + h4*4);
      *(unsigned long long*)(wt + wr*80 + h4*8) = pk4(v);
    }
    __syncthreads();
    #pragma unroll
    for (int j = 0; j < 4; j++){
      int ct = ctb + j*2;
      f32x4 acc = chainT(pt + mt*16*80, wt + ct*16*80, 80, 80, 1, lane);
      int g = cc0 + ct*16 + lr;
      if (g < CSZ2V){
        #pragma unroll
        for (int r2=0;r2<4;r2++){
          int row = mt*16 + lq*4 + r2;
          float v = acc[r2];
          exr[r2] += __expf(v);
          if (g == t2c[row]) l2p[r0+row] = v;
        }
      }
    }
  }
  #pragma unroll
  for (int r2=0;r2<4;r2++){
    float e = exr[r2];
    e += __shfl_xor(e,1); e += __shfl_xor(e,2); e += __shfl_xor(e,4); e += __shfl_xor(e,8);
    if (lr == 0) atomicAdd(&sums[4096 + r0 + mt*16 + lq*4 + r2], e);
  }
}

// ================= final gather =================

__global__ __launch_bounds__(256) void kfinal(const float* __restrict__ sums,
                                              const float* __restrict__ hlt, const float* __restrict__ hc1,
                                              const float* __restrict__ hc2, const float* __restrict__ l1p,
                                              const float* __restrict__ l2p, const int* __restrict__ tgt,
                                              float* __restrict__ out){
  __shared__ float red[256];
  int tid = threadIdx.x;
  float acc = 0.f;
  for (int n = tid; n < 2048; n += 256){
    int s = n >> 5, b = n & 31;
    int tg = tgt[b*NS + s];
    float lsh = logf(sums[n]);
    float v;
    if (tg < C1V) v = hlt[n] - lsh;
    else if (tg < C2V) v = (hc1[n] - lsh) + (l1p[n] - logf(sums[2048+n]));
    else v = (hc2[n] - lsh) + (l2p[n] - logf(sums[4096+n]));
    out[O_LP + n] = v;
    acc += v;
  }
  red[tid] = acc;
  __syncthreads();
  for (int off=128; off>0; off>>=1){ if (tid<off) red[tid] += red[tid+off]; __syncthreads(); }
  if (tid==0) out[O_LOSS] = -red[0] / 2048.0f;
}

extern "C" void kernel_launch(void* const* d_in, const int* in_sizes, int n_in,
                              void* d_out, int out_size, void* d_ws, size_t ws_size,
                              hipStream_t stream){
  (void)in_sizes; (void)n_in; (void)out_size; (void)ws_size;
  ScanArgs sa;
  sa.inputs = (const int*)d_in[0];
  sa.topics = (const int*)d_in[1];
  sa.out0   = (const float*)d_in[2];
  sa.h0in   = (const float*)d_in[3];
  sa.c0in   = (const float*)d_in[4];
  sa.mask   = (const float*)d_in[5];
  sa.cover  = (const float*)d_in[7];
  sa.emb    = (const float*)d_in[8];
  sa.Uf     = (const float*)d_in[9];
  sa.Ua     = (const float*)d_in[10];
  sa.Wa     = (const float*)d_in[11];
  sa.vaw    = (const float*)d_in[12];
  sa.vab    = (const float*)d_in[13];
  sa.wih0   = (const float*)d_in[14];
  sa.whh0   = (const float*)d_in[15];
  sa.bih0   = (const float*)d_in[16];
  sa.bhh0   = (const float*)d_in[17];
  sa.wih1   = (const float*)d_in[18];
  sa.whh1   = (const float*)d_in[19];
  sa.bih1   = (const float*)d_in[20];
  sa.bhh1   = (const float*)d_in[21];
  sa.ws  = (char*)d_ws;
  sa.out = (float*)d_out;

  char* wsb = (char*)d_ws;
  const int* target = (const int*)d_in[6];
  float* outf = (float*)d_out;

  hipMemsetAsync(wsb + SUMS_B, 0, 6144*sizeof(float), stream);
  hipMemsetAsync(wsb + BAR_B, 0, 16384, stream);   // preamble barrier flags + go
  hipMemsetAsync(wsb + SFLG_B, 0, 1536, stream);   // packed scan flags (A/C/D)

  static int lds_set = 0;
  if (!lds_set){
    hipFuncSetAttribute((const void*)scan_kernel,
                        hipFuncAttributeMaxDynamicSharedMemorySize, LDS_BYTES);
    hipFuncSetAttribute((const void*)kheadM,
                        hipFuncAttributeMaxDynamicSharedMemorySize, 66816);
    lds_set = 1;
  }

  void* args[] = { (void*)&sa };
  hipLaunchCooperativeKernel((void*)scan_kernel, dim3(208), dim3(256), args, LDS_BYTES, stream);

  const float* X = outf + O_OUTS;
  kproj<<<dim3(128,2),dim3(256),0,stream>>>(X, (const float*)d_in[23], (const float*)d_in[25],
                                            (float*)(wsb+P1_B), (float*)(wsb+P2_B));
  kheadM<<<dim3(64,8),dim3(256),66816,stream>>>(X, (const float*)d_in[22], target,
           (float*)(wsb+SUMS_B), (float*)(wsb+HLT_B), (float*)(wsb+HC1_B), (float*)(wsb+HC2_B));
  kt1M<<<dim3(64,8),dim3(256),0,stream>>>((const float*)(wsb+P1_B), (const float*)d_in[24], target,
           (float*)(wsb+SUMS_B), (float*)(wsb+L1P_B));
  kt2M<<<dim3(64,8),dim3(256),0,stream>>>((const float*)(wsb+P2_B), (const float*)d_in[26], target,
           (float*)(wsb+SUMS_B), (float*)(wsb+L2P_B));
  kfinal<<<dim3(1),dim3(256),0,stream>>>((const float*)(wsb+SUMS_B),
           (const float*)(wsb+HLT_B), (const float*)(wsb+HC1_B), (const float*)(wsb+HC2_B),
           (const float*)(wsb+L1P_B), (const float*)(wsb+L2P_B), target, outf);
}

// Round 10
// 2498.299 us; speedup vs baseline: 1.2671x; 1.1861x over previous
//
#include <hip/hip_runtime.h>
#include <cmath>

typedef __attribute__((ext_vector_type(8))) short short8;
typedef __attribute__((ext_vector_type(4))) float f32x4;

#define NB 32
#define NS 64
#define NK 5
#define NE 512
#define NH 512
#define C1V 2500
#define C2V 10000
#define CSZ1V 7500
#define CSZ2V 40000

// ---- workspace BYTE offsets ----
#define PWR_B   0u          // 4*512*512 f32 = 4MB (preamble only; aliased by ghE)
#define GHE_B   0u          // 64*2048*32 bf16 = 8MB (dead after scan; reused for bf16 weights)
#define HWB_B   0u          // bf16 hw   2502*512*2 = 2,562,048
#define T1WB_B  2562048u    // bf16 t1w2 7500*128*2 = 1,920,000
#define T2WB_B  4482048u    // bf16 t2w2 40000*32*2 = 2,560,000; end 7,042,048 < 8MB
#define QB_B    8388608u    // 32*512 bf16
#define H1B_B   8421376u
#define H0B_B   8454144u
#define PHI_B   8488192u    // 160 f32
#define P1_B    8488832u    // 2048*128 f32
#define P2_B    9537408u    // 2048*32 f32
#define SUMS_B  9799552u    // 3*2048 f32
#define HLT_B   9824128u
#define HC1_B   9832320u
#define HC2_B   9840512u
#define L1P_B   9848704u
#define L2P_B   9856896u
#define BAR_B   9865216u    // preamble flags 208*64B = 13312, go at +13312; memset 16384
#define SB2_B   9881600u    // 80*32 f32 score partials; end 9,891,840
#define SFLG_B  9891840u    // scan flags: A[0..79] C[80..207] D[208..335], 336*64B = 21504

// ---- d_out float offsets (verified) ----
#define O_LP   0
#define O_LOSS 2048
#define O_OUTS 2049
#define O_HF   1050625
#define O_CF   1083393
#define O_ATTN 1116161
#define O_COVF 1126401

// ---- LDS byte offsets (scan kernel) ----
#define ROWB 1040           // 520 bf16 per padded row (mult of 16 for b128 loads)
#define L_W1  0
#define L_WI  16640
#define L_W0  33280
#define L_ACT 49920
#define L_TP  83200
#define L_GH1 93440
#define L_GH0 95488
#define L_GB  97536
#define L_AL  99584
#define LDS_BYTES 100352
#define A_MI  0
#define A_ACT 33280
#define A_SCR 66560

__device__ __forceinline__ float sigmf(float x){ return 1.0f/(1.0f + expf(-x)); }

__device__ __forceinline__ unsigned short f2b16(float f){
  unsigned u = __float_as_uint(f);
  return (unsigned short)((u + 0x7fffu + ((u>>16)&1u)) >> 16);
}
__device__ __forceinline__ float b2f16(unsigned short s){ return __uint_as_float(((unsigned)s)<<16); }

// pack 4 f32 -> 4 bf16 in a u64
__device__ __forceinline__ unsigned long long pk4(float4 v){
  unsigned long long u = (unsigned long long)f2b16(v.x)
    | ((unsigned long long)f2b16(v.y) << 16)
    | ((unsigned long long)f2b16(v.z) << 32)
    | ((unsigned long long)f2b16(v.w) << 48);
  return u;
}

// ---- agent-scope (coherence-point) primitives ----
__device__ __forceinline__ unsigned ldf(unsigned* p){
  return __hip_atomic_load(p, __ATOMIC_RELAXED, __HIP_MEMORY_SCOPE_AGENT);
}
__device__ __forceinline__ void stf(unsigned* p, unsigned v){
  __hip_atomic_store(p, v, __ATOMIC_RELAXED, __HIP_MEMORY_SCOPE_AGENT);
}
__device__ __forceinline__ void sta64(unsigned long long* p, unsigned long long v){
  __hip_atomic_store(p, v, __ATOMIC_RELAXED, __HIP_MEMORY_SCOPE_AGENT);
}
__device__ __forceinline__ unsigned long long lda64(const unsigned long long* p){
  return __hip_atomic_load((unsigned long long*)p, __ATOMIC_RELAXED, __HIP_MEMORY_SCOPE_AGENT);
}
__device__ __forceinline__ void staf(float* p, float v){
  __hip_atomic_store(p, v, __ATOMIC_RELAXED, __HIP_MEMORY_SCOPE_AGENT);
}
__device__ __forceinline__ float ldaf(const float* p){
  return __hip_atomic_load((float*)p, __ATOMIC_RELAXED, __HIP_MEMORY_SCOPE_AGENT);
}

// ---- heavy barrier (preamble only) ----
__device__ __forceinline__ void bar_arrive(unsigned* flags, int wg, unsigned gen, int tid){
  __syncthreads();
  if (tid == 0){
    __threadfence();
    stf(flags + wg*16, gen);
  }
}
__device__ __forceinline__ void bar_collect(unsigned* flags, unsigned* go, unsigned gen,
                                            int first, int cnt, int tid){
  for (int i = tid; i < cnt; i += 256){
    unsigned* f = flags + (first + i)*16;
    while (ldf(f) < gen) __builtin_amdgcn_s_sleep(1);
  }
  __syncthreads();
  if (tid == 0) stf(go, gen);
}
__device__ __forceinline__ void bar_wait(unsigned* go, unsigned gen, int tid){
  if (tid == 0){
    while (ldf(go) < gen) __builtin_amdgcn_s_sleep(1);
    __threadfence();
  }
  __syncthreads();
}

// ---- light scan-loop sync (round-6 proven: 1 line/producer, wide poll) ----
__device__ __forceinline__ void waitsf(unsigned* SF, int first, int cnt, unsigned gen, int tid){
  for (int i = tid; i < cnt; i += 256){
    unsigned* f = SF + (first + i)*16;
    while (ldf(f) < gen) __builtin_amdgcn_s_sleep(1);
  }
  __syncthreads();
}

// D[m][n] += A[m][k]*B[n][k] over K=512, one 16x16 tile, rows padded ROWB.
__device__ __forceinline__ f32x4 chain16(const char* Abase, const char* Bbase, int lane){
  f32x4 acc = {0.f,0.f,0.f,0.f};
  int lr = lane & 15, lq = lane >> 4;
  const char* ap = Abase + lr*ROWB + lq*16;
  const char* bp = Bbase + lr*ROWB + lq*16;
  #pragma unroll
  for (int ks=0; ks<16; ks++){
    short8 af = *(const short8*)(ap + ks*64);
    short8 bf = *(const short8*)(bp + ks*64);
    acc = __builtin_amdgcn_mfma_f32_16x16x32_bf16(af, bf, acc, 0, 0, 0);
  }
  return acc;
}

// generic-stride, generic-K chain: K = nks*32. strides must be multiples of 16B.
__device__ __forceinline__ f32x4 chainT(const char* Abase, const char* Bbase,
                                        int sA, int sB, int nks, int lane){
  f32x4 acc = {0.f,0.f,0.f,0.f};
  int lr = lane & 15, lq = lane >> 4;
  const char* ap = Abase + lr*sA + lq*16;
  const char* bp = Bbase + lr*sB + lq*16;
  for (int ks=0; ks<nks; ks++){
    short8 af = *(const short8*)(ap + ks*64);
    short8 bf = *(const short8*)(bp + ks*64);
    acc = __builtin_amdgcn_mfma_f32_16x16x32_bf16(af, bf, acc, 0, 0, 0);
  }
  return acc;
}

__device__ __forceinline__ void stage32(const unsigned short* g, char* dst, int tid){
  int b = tid & 31, seg = tid >> 5;
  const float4* s4 = (const float4*)(g + (size_t)b*512 + seg*64);
  float4* d4 = (float4*)(dst + b*ROWB + seg*128);
  #pragma unroll
  for (int i=0;i<8;i++) d4[i] = s4[i];
}

// agent-scope variant used inside the scan loop
__device__ __forceinline__ void stage32a(const unsigned short* g, char* dst, int tid){
  int b = tid & 31, seg = tid >> 5;
  const unsigned long long* s8 = (const unsigned long long*)(g + (size_t)b*512 + seg*64);
  unsigned long long* d8 = (unsigned long long*)(dst + b*ROWB + seg*128);
  #pragma unroll
  for (int i=0;i<16;i++) d8[i] = lda64(s8 + i);
}

__device__ __forceinline__ float dot512(const float* __restrict__ x, const float* __restrict__ w){
  const float4* x4 = (const float4*)x;
  const float4* w4 = (const float4*)w;
  float a0=0.f,a1=0.f,a2=0.f,a3=0.f;
  #pragma unroll 8
  for (int h=0; h<128; h++){
    float4 xx = x4[h]; float4 ww = w4[h];
    a0 = fmaf(xx.x, ww.x, a0); a1 = fmaf(xx.y, ww.y, a1);
    a2 = fmaf(xx.z, ww.z, a2); a3 = fmaf(xx.w, ww.w, a3);
  }
  return (a0+a1)+(a2+a3);
}

struct ScanArgs {
  const int* inputs; const int* topics; const float* out0;
  const float* h0in; const float* c0in; const float* mask; const float* cover;
  const float* emb; const float* Uf; const float* Ua; const float* Wa;
  const float* vaw; const float* vab;
  const float* wih0; const float* whh0; const float* bih0; const float* bhh0;
  const float* wih1; const float* whh1; const float* bih1; const float* bhh1;
  char* ws; float* out;
};

// ====================== scan kernel: BYTE-IDENTICAL to round-6 passing version ======================
// 208 wgs x 256 threads. wgs 0..79 attention (wg0 = preamble collector), 80..207 LSTM.
__global__ __launch_bounds__(256) void scan_kernel(ScanArgs a){
  extern __shared__ char sm[];
  const int wg = blockIdx.x, tid = threadIdx.x;
  const int lane = tid & 63, wave = tid >> 6;
  const int GT = gridDim.x * blockDim.x;
  const int gt = wg*256 + tid;
  char* wsb = a.ws;
  unsigned* bflags = (unsigned*)(wsb + BAR_B);
  unsigned* bgo    = (unsigned*)(wsb + BAR_B + 13312);
  unsigned* SF     = (unsigned*)(wsb + SFLG_B);
  const bool isAttn = (wg < 80);
  const int head = wg >> 4;
  const int e0 = (wg & 15) * 32;
  const int lw = wg - 80;
  const int u0 = lw * 4;

  f32x4 pkr = {0.f,0.f,0.f,0.f};
  float var[4] = {0.f,0.f,0.f,0.f};
  float b0r[4] = {0,0,0,0}, b1r[4] = {0,0,0,0};
  float c0r = 0.f, c1r = 0.f;
  float covr[NK] = {0,0,0,0,0}, phir[NK] = {1,1,1,1,1};

  // ================= P0a: inits + phi =================
  {
    unsigned short* qb  = (unsigned short*)(wsb + QB_B);
    unsigned short* h1b = (unsigned short*)(wsb + H1B_B);
    unsigned short* h0b = (unsigned short*)(wsb + H0B_B);
    for (int i = gt; i < NB*NH; i += GT){
      qb[i]  = f2b16(a.out0[i]);
      h1b[i] = f2b16(a.h0in[NB*NH + i]);
      h0b[i] = f2b16(a.h0in[i]);
    }
    if (gt < 160){
      int b = gt/NK, k = gt%NK;
      float ms = 0.f; for (int s=0;s<NS;s++) ms += a.mask[b*NS+s];
      float acc = 0.f;
      for (int kk=0; kk<NK; kk++){
        const float* te = a.emb + (size_t)a.topics[b*NK+kk]*NE;
        const float* uf = a.Uf + (size_t)k*(NK*NE) + kk*NE;
        acc += dot512(te, uf);
      }
      ((float*)(wsb + PHI_B))[gt] = ms * sigmf(acc);
    }
  }
  bar_arrive(bflags, wg, 1, tid);
  if (wg==0) bar_collect(bflags, bgo, 1, 0, 208, tid);
  bar_wait(bgo, 1, tid);

  // ================= P1: Wa powers (fp32) =================
  for (int r=0; r<4; r++){
    const float* Asrc = (r==0) ? a.Wa : (const float*)(wsb + PWR_B) + (size_t)(r-1)*NH*NH;
    float* Mo = (float*)(wsb + PWR_B) + (size_t)r*NH*NH;
    for (int d = gt; d < NH*NH; d += GT){
      int row = d >> 9, col = d & 511;
      const float* ar = Asrc + (size_t)row*NH;
      float acc = 0.f;
      for (int k2=0;k2<NH;k2++) acc = fmaf(ar[k2], a.Wa[(size_t)k2*NH + col], acc);
      Mo[d] = acc;
    }
    unsigned g = 2 + r;
    bar_arrive(bflags, wg, g, tid);
    if (wg==0) bar_collect(bflags, bgo, g, 0, 208, tid);
    bar_wait(bgo, g, tid);
  }

  // ================= P2: attn pk+Mi; lstm tp =================
  if (isAttn){
    for (int idx=tid; idx<32*512; idx+=256){
      int r = idx>>9, k = idx&511;
      *(unsigned short*)(sm + A_MI + r*ROWB + k*2) = f2b16(a.Ua[(size_t)(e0+r)*NE + k]);
    }
    for (int idx=tid; idx<32*512; idx+=256){
      int r = idx>>9, k = idx&511;
      int tok = a.topics[r*NK + head];
      *(unsigned short*)(sm + A_ACT + r*ROWB + k*2) = f2b16(a.emb[(size_t)tok*NE + k]);
    }
    __syncthreads();
    {
      int mt = wave&1, nt = wave>>1;
      pkr = chain16(sm + A_MI + mt*16*ROWB, sm + A_ACT + nt*16*ROWB, lane);
      int lq = lane>>4;
      #pragma unroll
      for (int r2=0;r2<4;r2++) var[r2] = a.vaw[e0 + mt*16 + lq*4 + r2];
    }
    __syncthreads();
    const float* Msrc = (head==0) ? a.Wa : (const float*)(wsb + PWR_B) + (size_t)(head-1)*NH*NH;
    for (int idx=tid; idx<32*512; idx+=256){
      int r = idx>>9, k = idx&511;
      *(unsigned short*)(sm + A_MI + r*ROWB + k*2) = f2b16(Msrc[(size_t)(e0+r)*NH + k]);
    }
  } else {
    for (int idx=tid; idx<16*512; idx+=256){
      int rr = idx>>9, k = idx&511;
      int j = (rr>>2)*NH + u0 + (rr&3);
      *(unsigned short*)(sm + L_WI + rr*ROWB + k*2) = f2b16(a.wih0[(size_t)j*(2*NE) + NE + k]);
    }
    __syncthreads();
    for (int rnd=0; rnd<5; rnd++){
      for (int idx=tid; idx<32*512; idx+=256){
        int r = idx>>9, k = idx&511;
        int tok = a.topics[rnd*32 + r];
        *(unsigned short*)(sm + L_ACT + r*ROWB + k*2) = f2b16(a.emb[(size_t)tok*NE + k]);
      }
      __syncthreads();
      if (wave < 2){
        f32x4 acc = chain16(sm + L_ACT + wave*16*ROWB, sm + L_WI, lane);
        int lr = lane&15, lq = lane>>4;
        #pragma unroll
        for (int r2=0;r2<4;r2++){
          int row = rnd*32 + wave*16 + lq*4 + r2;
          int bb = row/5, kk = row - bb*5;
          *(float*)(sm + L_TP + (((kk*16) + lr)*32 + bb)*4) = acc[r2];
        }
      }
      __syncthreads();
    }
  }
  // g6: attn done reading powers -> lstm may overwrite with ghE
  bar_arrive(bflags, wg, 6, tid);
  if (wg==0) bar_collect(bflags, bgo, 6, 0, 208, tid);
  if (!isAttn) bar_wait(bgo, 6, tid);

  // ================= P4 (lstm only): ghE + weights + regs + gh0 init =================
  if (!isAttn){
    for (int idx=tid; idx<16*512; idx+=256){
      int rr = idx>>9, k = idx&511;
      int j = (rr>>2)*NH + u0 + (rr&3);
      *(unsigned short*)(sm + 66560 + rr*ROWB + k*2) = f2b16(a.wih0[(size_t)j*(2*NE) + k]);
    }
    __syncthreads();
    unsigned short* gE = (unsigned short*)(wsb + GHE_B);
    for (int it=0; it<32; it++){
      for (int idx=tid; idx<64*512; idx+=256){
        int r = idx>>9, k = idx&511;
        int grow = it*64 + r;
        int tt = grow>>5, bb = grow&31;
        int tok = a.inputs[bb*NS + tt];
        *(unsigned short*)(sm + r*ROWB + k*2) = f2b16(a.emb[(size_t)tok*NE + k]);
      }
      __syncthreads();
      {
        f32x4 acc = chain16(sm + wave*16*ROWB, sm + 66560, lane);
        int lr = lane&15, lq = lane>>4;
        #pragma unroll
        for (int r2=0;r2<4;r2++){
          int grow = it*64 + wave*16 + lq*4 + r2;
          int tt = grow>>5, bb = grow&31;
          int jg = (lr>>2)*NH + u0 + (lr&3);
          gE[((size_t)tt*2048 + jg)*32 + bb] = f2b16(acc[r2]);
        }
      }
      __syncthreads();
    }
    for (int idx=tid; idx<16*512; idx+=256){
      int rr = idx>>9, k = idx&511;
      int j = (rr>>2)*NH + u0 + (rr&3);
      *(unsigned short*)(sm + L_W1 + rr*ROWB + k*2) = f2b16(a.whh1[(size_t)j*NH + k]);
      *(unsigned short*)(sm + L_WI + rr*ROWB + k*2) = f2b16(a.wih1[(size_t)j*NH + k]);
      *(unsigned short*)(sm + L_W0 + rr*ROWB + k*2) = f2b16(a.whh0[(size_t)j*NH + k]);
    }
    if (tid < 128){
      int bb = tid&31, ur = tid>>5;
      #pragma unroll
      for (int g=0; g<4; g++){
        int j = g*NH + u0 + ur;
        b0r[g] = a.bih0[j] + a.bhh0[j];
        b1r[g] = a.bih1[j] + a.bhh1[j];
      }
      c0r = a.c0in[(size_t)bb*NH + u0 + ur];
      c1r = a.c0in[(size_t)NB*NH + bb*NH + u0 + ur];
    }
    if (tid < 32){
      const float* phiG = (const float*)(wsb + PHI_B);
      #pragma unroll
      for (int k=0;k<NK;k++){ covr[k] = a.cover[tid*NK + k]; phir[k] = phiG[tid*NK + k]; }
    }
    __syncthreads();
    stage32((const unsigned short*)(wsb + H0B_B), sm + L_ACT, tid);
    __syncthreads();
    if (wave & 1){
      int nt = wave>>1;
      f32x4 acc = chain16(sm + L_W0, sm + L_ACT + nt*16*ROWB, lane);
      int lr = lane&15, lq = lane>>4;
      #pragma unroll
      for (int r2=0;r2<4;r2++)
        *(float*)(sm + L_GH0 + ((lq*4+r2)*32 + nt*16 + lr)*4) = acc[r2];
    }
    __syncthreads();
  }

  // ================= scan: fence-free 1-hop flag syncs =================
  for (int t=0; t<NS; t++){
    unsigned gT = (unsigned)t, gT1 = (unsigned)(t+1);
    if (isAttn){
      waitsf(SF, 208, 128, gT, tid);                  // h1(t-1) fully published
      stage32a((const unsigned short*)(wsb + QB_B), sm + A_ACT, tid);
      __syncthreads();
      int mt = wave&1, nt = wave>>1;
      f32x4 acc = chain16(sm + A_MI + mt*16*ROWB, sm + A_ACT + nt*16*ROWB, lane);
      float v = 0.f;
      #pragma unroll
      for (int r2=0;r2<4;r2++) v += tanhf(acc[r2] + pkr[r2]) * var[r2];
      v += __shfl_xor(v, 16);
      v += __shfl_xor(v, 32);
      if ((lane>>4)==0) *(float*)(sm + A_SCR + (wave*16 + (lane&15))*4) = v;
      __syncthreads();
      if (tid < 32){
        int nt2 = tid>>4, bh = tid&15;
        float s = *(const float*)(sm + A_SCR + ((nt2*2)*16 + bh)*4)
                + *(const float*)(sm + A_SCR + ((nt2*2+1)*16 + bh)*4);
        staf(((float*)(wsb + SB2_B)) + wg*32 + tid, s);
      }
      __syncthreads();                                // drains agent stores
      if (tid == 0) stf(SF + wg*16, gT1);             // publish scores(t)
    } else {
      waitsf(SF, 208, 128, gT, tid);                  // h1(t-1) fully published
      stage32a((const unsigned short*)(wsb + H1B_B), sm + L_ACT, tid);
      __syncthreads();
      if (wave < 2){
        f32x4 acc = chain16(sm + L_W1, sm + L_ACT + wave*16*ROWB, lane);
        int lr = lane&15, lq = lane>>4;
        #pragma unroll
        for (int r2=0;r2<4;r2++)
          *(float*)(sm + L_GH1 + ((lq*4+r2)*32 + wave*16 + lr)*4) = acc[r2];
      }
      waitsf(SF, 0, 80, gT1, tid);                    // scores(t) ready

      // ---- Phase C ----
      if (tid < 160){
        int k = tid>>5, b = tid&31;
        const float* sb2 = (const float*)(wsb + SB2_B);
        float s = 0.f;
        #pragma unroll
        for (int es=0; es<16; es++) s += ldaf(sb2 + (k*16+es)*32 + b);
        *(float*)(sm + L_GB + tid*4) = s;
      }
      __syncthreads();
      if (tid < 32){
        float vb = a.vab[0];
        float sc[NK], mx = -1e30f;
        #pragma unroll
        for (int k=0;k<NK;k++){
          float s = (*(const float*)(sm + L_GB + (k*32+tid)*4) + vb) * covr[k];
          sc[k] = s; mx = fmaxf(mx, s);
        }
        float sum = 0.f;
        #pragma unroll
        for (int k=0;k<NK;k++){ sc[k] = expf(sc[k]-mx); sum += sc[k]; }
        float inv = 1.0f/sum;
        #pragma unroll
        for (int k=0;k<NK;k++){
          float al = sc[k]*inv;
          *(float*)(sm + L_AL + (tid*NK+k)*4) = al;
          covr[k] = covr[k] - al/phir[k];
          if (lw == 0){
            a.out[O_ATTN + (size_t)(t*NB + tid)*NK + k] = al;
            if (t == NS-1) a.out[O_COVF + tid*NK + k] = covr[k];
          }
        }
      }
      __syncthreads();
      if (tid < 128){
        int bb = tid&31, ur = tid>>5;
        const unsigned short* gE = (const unsigned short*)(wsb + GHE_B);
        float al[NK];
        #pragma unroll
        for (int k=0;k<NK;k++) al[k] = *(const float*)(sm + L_AL + (bb*NK+k)*4);
        float g4[4];
        #pragma unroll
        for (int g=0; g<4; g++){
          int rr = g*4 + ur;
          float x = b2f16(gE[((size_t)t*2048 + g*NH + u0 + ur)*32 + bb]);
          x += *(const float*)(sm + L_GH0 + (rr*32 + bb)*4);
          x += b0r[g];
          #pragma unroll
          for (int k=0;k<NK;k++) x += al[k] * *(const float*)(sm + L_TP + ((k*16+rr)*32 + bb)*4);
          g4[g] = x;
        }
        float cn = sigmf(g4[1])*c0r + sigmf(g4[0])*tanhf(g4[2]);
        float hn = sigmf(g4[3])*tanhf(cn);
        c0r = cn;
        ((unsigned short*)(sm + L_ACT))[bb*4 + ur] = f2b16(hn);
        if (t == NS-1){
          a.out[O_HF + (size_t)bb*NH + u0 + ur] = hn;
          a.out[O_CF + (size_t)bb*NH + u0 + ur] = cn;
        }
      }
      __syncthreads();
      if (tid < 32){
        unsigned long long v = *(const unsigned long long*)((const unsigned short*)(sm + L_ACT) + tid*4);
        sta64((unsigned long long*)((unsigned short*)(wsb + H0B_B) + (size_t)tid*NH + u0), v);
      }
      __syncthreads();
      if (tid == 0) stf(SF + (80+lw)*16, gT1);        // publish h0 slice(t)
      waitsf(SF, 80, 128, gT1, tid);                  // h0(t) fully published

      // ---- Phase D ----
      stage32a((const unsigned short*)(wsb + H0B_B), sm + L_ACT, tid);
      __syncthreads();
      {
        int mat = wave&1, nt = wave>>1;
        f32x4 acc = chain16(sm + (mat ? L_W0 : L_WI), sm + L_ACT + nt*16*ROWB, lane);
        int lr = lane&15, lq = lane>>4;
        char* dst = sm + (mat ? L_GH0 : L_GB);
        #pragma unroll
        for (int r2=0;r2<4;r2++)
          *(float*)(dst + ((lq*4+r2)*32 + nt*16 + lr)*4) = acc[r2];
      }
      __syncthreads();
      if (tid < 128){
        int bb = tid&31, ur = tid>>5;
        float g4[4];
        #pragma unroll
        for (int g=0; g<4; g++){
          int rr = g*4+ur;
          g4[g] = *(const float*)(sm + L_GB + (rr*32+bb)*4)
                + *(const float*)(sm + L_GH1 + (rr*32+bb)*4) + b1r[g];
        }
        float cn = sigmf(g4[1])*c1r + sigmf(g4[0])*tanhf(g4[2]);
        float hn = sigmf(g4[3])*tanhf(cn);
        c1r = cn;
        ((unsigned short*)(sm + L_ACT))[bb*4 + ur] = f2b16(hn);
        a.out[O_OUTS + (size_t)(t*NB + bb)*NH + u0 + ur] = hn;
        if (t == NS-1){
          a.out[O_HF + (size_t)(NB + bb)*NH + u0 + ur] = hn;
          a.out[O_CF + (size_t)(NB + bb)*NH + u0 + ur] = cn;
        }
      }
      __syncthreads();
      if (tid < 32){
        unsigned long long v = *(const unsigned long long*)((const unsigned short*)(sm + L_ACT) + tid*4);
        sta64((unsigned long long*)((unsigned short*)(wsb + QB_B)  + (size_t)tid*NH + u0), v);
        sta64((unsigned long long*)((unsigned short*)(wsb + H1B_B) + (size_t)tid*NH + u0), v);
      }
      __syncthreads();
      if (tid == 0) stf(SF + (208+lw)*16, gT1);       // publish h1 slice(t)
    }
  }
}

// ================= one-time weight conversion (runs after scan; GHE region is dead) =================
__global__ __launch_bounds__(256) void kconv(const float* __restrict__ hw,
                                             const float* __restrict__ t1w2,
                                             const float* __restrict__ t2w2,
                                             char* __restrict__ wsb){
  unsigned gid = blockIdx.x*256 + threadIdx.x, GT = gridDim.x*256;
  unsigned long long* o0 = (unsigned long long*)(wsb + HWB_B);
  const float4* s0 = (const float4*)hw;
  for (unsigned i = gid; i < 320256u; i += GT) o0[i] = pk4(s0[i]);    // 2502*512/4
  unsigned long long* o1 = (unsigned long long*)(wsb + T1WB_B);
  const float4* s1 = (const float4*)t1w2;
  for (unsigned i = gid; i < 240000u; i += GT) o1[i] = pk4(s1[i]);    // 7500*128/4
  unsigned long long* o2 = (unsigned long long*)(wsb + T2WB_B);
  const float4* s2 = (const float4*)t2w2;
  for (unsigned i = gid; i < 320000u; i += GT) o2[i] = pk4(s2[i]);    // 40000*32/4
}

// ================= adaptive log-softmax tail: MFMA GEMMs, bf16 weights =================

// P1 = X @ t1w1.T, P2 = X @ t2w1.T  (round-6 kernel, unchanged)
__global__ __launch_bounds__(256) void kproj(const float* __restrict__ X,
                                             const float* __restrict__ t1w1,
                                             const float* __restrict__ t2w1,
                                             float* __restrict__ P1, float* __restrict__ P2){
  __shared__ float xs[16*516];
  int r0 = blockIdx.x*16, tid = threadIdx.x;
  int yy = blockIdx.y;
  for (int idx=tid; idx<16*512; idx+=256){ int rl=idx>>9, h=idx&511; xs[rl*516+h] = X[(size_t)(r0+rl)*NH + h]; }
  __syncthreads();
  if (yy == 0){
    for (int k=0;k<4;k++){
      int d = tid + 256*k; int rl = d & 15, c = d >> 4;
      P1[(size_t)(r0+rl)*128 + c] = dot512(xs + rl*516, t1w1 + (size_t)c*NH);
    }
  } else {
    for (int k=4;k<8;k++){
      int d = tid + 256*k; int rl = d & 15, c = d >> 4;
      P1[(size_t)(r0+rl)*128 + c] = dot512(xs + rl*516, t1w1 + (size_t)c*NH);
    }
    for (int k=0;k<2;k++){
      int d = tid + 256*k; int rl = d & 15, c = d >> 4;
      P2[(size_t)(r0+rl)*32 + c] = dot512(xs + rl*516, t2w1 + (size_t)c*NH);
    }
  }
}

// HEAD: logits = X(2048x512) @ hw.T(512x2502). Grid (64 row-blocks, 8 col-strips).
// bf16 weights from ws (pre-converted). Strip = 10 chunks x 32 cols.
__global__ __launch_bounds__(256) void kheadM(const float* __restrict__ X,
                                              const char* __restrict__ wsb,
                                              const int* __restrict__ tgt,
                                              float* __restrict__ sums,
                                              float* __restrict__ hlt, float* __restrict__ hc1,
                                              float* __restrict__ hc2){
  extern __shared__ char sm[];
  int* caps = (int*)(sm + 66560);
  const unsigned long long* hwb = (const unsigned long long*)(wsb + HWB_B);
  int r0 = blockIdx.x*32, tid = threadIdx.x;
  int strip = blockIdx.y;
  int lane = tid&63, wave = tid>>6;
  int lr = lane&15, lq = lane>>4;
  // stage X rows (f32 -> bf16, once per block)
  #pragma unroll
  for (int it = 0; it < 16; it++){
    int idx = tid + it*256;
    int rl = idx>>7, h4 = idx&127;
    float4 v = *(const float4*)(X + (size_t)(r0+rl)*NH + h4*4);
    *(unsigned long long*)(sm + rl*ROWB + h4*8) = pk4(v);
  }
  if (tid < 32){
    int row = r0+tid;
    int tg = tgt[(row&31)*NS + (row>>5)];
    caps[tid] = tg < C1V ? tg : (C1V-1);
  }
  int mt = wave&1, nt = wave>>1;
  float exr[4] = {0.f,0.f,0.f,0.f};
  for (int ch = 0; ch < 10; ch++){
    int cc0 = (strip*10 + ch)*32;
    __syncthreads();
    #pragma unroll
    for (int it = 0; it < 16; it++){
      int idx = tid + it*256;                 // 32 rows x 128 u64
      int wr = idx>>7, h8 = idx&127;
      int col = cc0 + wr; if (col >= C1V+2) col = 0;
      *(unsigned long long*)(sm + 33280 + wr*ROWB + h8*8) = hwb[(size_t)col*128 + h8];
    }
    __syncthreads();
    f32x4 acc = chain16(sm + mt*16*ROWB, sm + 33280 + nt*16*ROWB, lane);
    int g = cc0 + nt*16 + lr;
    if (g < C1V+2){
      #pragma unroll
      for (int r2=0;r2<4;r2++){
        int row = mt*16 + lq*4 + r2;
        float v = acc[r2];
        exr[r2] += __expf(v);
        if (g == caps[row]) hlt[r0+row] = v;
        else if (g == C1V) hc1[r0+row] = v;
        else if (g == C1V+1) hc2[r0+row] = v;
      }
    }
  }
  #pragma unroll
  for (int r2=0;r2<4;r2++){
    float e = exr[r2];
    e += __shfl_xor(e,1); e += __shfl_xor(e,2); e += __shfl_xor(e,4); e += __shfl_xor(e,8);
    if (lr == 0) atomicAdd(&sums[r0 + mt*16 + lq*4 + r2], e);
  }
}

// TAIL1: logits = P1(2048x128) @ t1w2.T(128x7500). Grid (64, 8); strip = 30 chunks x 32 cols.
__global__ __launch_bounds__(256) void kt1M(const float* __restrict__ P1,
                                            const char* __restrict__ wsb,
                                            const int* __restrict__ tgt,
                                            float* __restrict__ sums, float* __restrict__ l1p){
  __shared__ __align__(16) char pt[32*272];
  __shared__ __align__(16) char wt[32*272];
  __shared__ int t1c[32];
  const unsigned long long* w1b = (const unsigned long long*)(wsb + T1WB_B);
  int r0 = blockIdx.x*32, tid = threadIdx.x;
  int strip = blockIdx.y;
  int lane = tid&63, wave = tid>>6;
  int lr = lane&15, lq = lane>>4;
  #pragma unroll
  for (int it = 0; it < 4; it++){
    int idx = tid + it*256;
    int rl = idx>>5, h4 = idx&31;
    float4 v = *(const float4*)(P1 + (size_t)(r0+rl)*128 + h4*4);
    *(unsigned long long*)(pt + rl*272 + h4*8) = pk4(v);
  }
  if (tid < 32){
    int row = r0+tid;
    int tg = tgt[(row&31)*NS + (row>>5)];
    t1c[tid] = (tg >= C1V && tg < C2V) ? (tg - C1V) : -1;
  }
  int mt = wave&1, nt = wave>>1;
  float exr[4] = {0.f,0.f,0.f,0.f};
  for (int ch = 0; ch < 30; ch++){
    int cc0 = (strip*30 + ch)*32;
    __syncthreads();
    #pragma unroll
    for (int it = 0; it < 4; it++){
      int idx = tid + it*256;                 // 32 rows x 32 u64
      int wr = idx>>5, h8 = idx&31;
      int col = cc0 + wr; if (col >= CSZ1V) col = 0;
      *(unsigned long long*)(wt + wr*272 + h8*8) = w1b[(size_t)col*32 + h8];
    }
    __syncthreads();
    f32x4 acc = chainT(pt + mt*16*272, wt + nt*16*272, 272, 272, 4, lane);
    int g = cc0 + nt*16 + lr;
    if (g < CSZ1V){
      #pragma unroll
      for (int r2=0;r2<4;r2++){
        int row = mt*16 + lq*4 + r2;
        float v = acc[r2];
        exr[r2] += __expf(v);
        if (g == t1c[row]) l1p[r0+row] = v;
      }
    }
  }
  #pragma unroll
  for (int r2=0;r2<4;r2++){
    float e = exr[r2];
    e += __shfl_xor(e,1); e += __shfl_xor(e,2); e += __shfl_xor(e,4); e += __shfl_xor(e,8);
    if (lr == 0) atomicAdd(&sums[2048 + r0 + mt*16 + lq*4 + r2], e);
  }
}

// TAIL2: logits = P2(2048x32) @ t2w2.T(32x40000). Grid (64, 8); strip = 40 chunks x 128 cols.
__global__ __launch_bounds__(256) void kt2M(const float* __restrict__ P2,
                                            const char* __restrict__ wsb,
                                            const int* __restrict__ tgt,
                                            float* __restrict__ sums, float* __restrict__ l2p){
  __shared__ __align__(16) char pt[32*80];
  __shared__ __align__(16) char wt[128*80];
  __shared__ int t2c[32];
  const unsigned long long* w2b = (const unsigned long long*)(wsb + T2WB_B);
  int r0 = blockIdx.x*32, tid = threadIdx.x;
  int strip = blockIdx.y;
  int lane = tid&63, wave = tid>>6;
  int lr = lane&15, lq = lane>>4;
  {
    int idx = tid;
    if (idx < 32*8){
      int rl = idx>>3, h4 = idx&7;
      float4 v = *(const float4*)(P2 + (size_t)(r0+rl)*32 + h4*4);
      *(unsigned long long*)(pt + rl*80 + h4*8) = pk4(v);
    }
  }
  if (tid < 32){
    int row = r0+tid;
    int tg = tgt[(row&31)*NS + (row>>5)];
    t2c[tid] = (tg >= C2V) ? (tg - C2V) : -1;
  }
  int mt = wave&1, ctb = wave>>1;
  float exr[4] = {0.f,0.f,0.f,0.f};
  for (int ch = 0; ch < 40; ch++){
    int cc0 = (strip*40 + ch)*128;
    __syncthreads();
    #pragma unroll
    for (int it = 0; it < 4; it++){
      int idx = tid + it*256;                 // 128 rows x 8 u64
      int wr = idx>>3, h8 = idx&7;
      int col = cc0 + wr; if (col >= CSZ2V) col = 0;
      *(unsigned long long*)(wt + wr*80 + h8*8) = w2b[(size_t)col*8 + h8];
    }
    __syncthreads();
    #pragma unroll
    for (int j = 0; j < 4; j++){
      int ct = ctb + j*2;
      f32x4 acc = chainT(pt + mt*16*80, wt + ct*16*80, 80, 80, 1, lane);
      int g = cc0 + ct*16 + lr;
      if (g < CSZ2V){
        #pragma unroll
        for (int r2=0;r2<4;r2++){
          int row = mt*16 + lq*4 + r2;
          float v = acc[r2];
          exr[r2] += __expf(v);
          if (g == t2c[row]) l2p[r0+row] = v;
        }
      }
    }
  }
  #pragma unroll
  for (int r2=0;r2<4;r2++){
    float e = exr[r2];
    e += __shfl_xor(e,1); e += __shfl_xor(e,2); e += __shfl_xor(e,4); e += __shfl_xor(e,8);
    if (lr == 0) atomicAdd(&sums[4096 + r0 + mt*16 + lq*4 + r2], e);
  }
}

// ================= final gather =================

__global__ __launch_bounds__(256) void kfinal(const float* __restrict__ sums,
                                              const float* __restrict__ hlt, const float* __restrict__ hc1,
                                              const float* __restrict__ hc2, const float* __restrict__ l1p,
                                              const float* __restrict__ l2p, const int* __restrict__ tgt,
                                              float* __restrict__ out){
  __shared__ float red[256];
  int tid = threadIdx.x;
  float acc = 0.f;
  for (int n = tid; n < 2048; n += 256){
    int s = n >> 5, b = n & 31;
    int tg = tgt[b*NS + s];
    float lsh = logf(sums[n]);
    float v;
    if (tg < C1V) v = hlt[n] - lsh;
    else if (tg < C2V) v = (hc1[n] - lsh) + (l1p[n] - logf(sums[2048+n]));
    else v = (hc2[n] - lsh) + (l2p[n] - logf(sums[4096+n]));
    out[O_LP + n] = v;
    acc += v;
  }
  red[tid] = acc;
  __syncthreads();
  for (int off=128; off>0; off>>=1){ if (tid<off) red[tid] += red[tid+off]; __syncthreads(); }
  if (tid==0) out[O_LOSS] = -red[0] / 2048.0f;
}

extern "C" void kernel_launch(void* const* d_in, const int* in_sizes, int n_in,
                              void* d_out, int out_size, void* d_ws, size_t ws_size,
                              hipStream_t stream){
  (void)in_sizes; (void)n_in; (void)out_size; (void)ws_size;
  ScanArgs sa;
  sa.inputs = (const int*)d_in[0];
  sa.topics = (const int*)d_in[1];
  sa.out0   = (const float*)d_in[2];
  sa.h0in   = (const float*)d_in[3];
  sa.c0in   = (const float*)d_in[4];
  sa.mask   = (const float*)d_in[5];
  sa.cover  = (const float*)d_in[7];
  sa.emb    = (const float*)d_in[8];
  sa.Uf     = (const float*)d_in[9];
  sa.Ua     = (const float*)d_in[10];
  sa.Wa     = (const float*)d_in[11];
  sa.vaw    = (const float*)d_in[12];
  sa.vab    = (const float*)d_in[13];
  sa.wih0   = (const float*)d_in[14];
  sa.whh0   = (const float*)d_in[15];
  sa.bih0   = (const float*)d_in[16];
  sa.bhh0   = (const float*)d_in[17];
  sa.wih1   = (const float*)d_in[18];
  sa.whh1   = (const float*)d_in[19];
  sa.bih1   = (const float*)d_in[20];
  sa.bhh1   = (const float*)d_in[21];
  sa.ws  = (char*)d_ws;
  sa.out = (float*)d_out;

  char* wsb = (char*)d_ws;
  const int* target = (const int*)d_in[6];
  float* outf = (float*)d_out;

  hipMemsetAsync(wsb + SUMS_B, 0, 6144*sizeof(float), stream);
  hipMemsetAsync(wsb + BAR_B, 0, 16384, stream);   // preamble barrier flags + go
  hipMemsetAsync(wsb + SFLG_B, 0, 21504, stream);  // scan-loop flags (A/C/D)

  static int lds_set = 0;
  if (!lds_set){
    hipFuncSetAttribute((const void*)scan_kernel,
                        hipFuncAttributeMaxDynamicSharedMemorySize, LDS_BYTES);
    hipFuncSetAttribute((const void*)kheadM,
                        hipFuncAttributeMaxDynamicSharedMemorySize, 66816);
    lds_set = 1;
  }

  void* args[] = { (void*)&sa };
  hipLaunchCooperativeKernel((void*)scan_kernel, dim3(208), dim3(256), args, LDS_BYTES, stream);

  const float* X = outf + O_OUTS;
  kconv<<<dim3(512),dim3(256),0,stream>>>((const float*)d_in[22], (const float*)d_in[24],
                                          (const float*)d_in[26], wsb);
  kproj<<<dim3(128,2),dim3(256),0,stream>>>(X, (const float*)d_in[23], (const float*)d_in[25],
                                            (float*)(wsb+P1_B), (float*)(wsb+P2_B));
  kheadM<<<dim3(64,8),dim3(256),66816,stream>>>(X, (const char*)wsb, target,
           (float*)(wsb+SUMS_B), (float*)(wsb+HLT_B), (float*)(wsb+HC1_B), (float*)(wsb+HC2_B));
  kt1M<<<dim3(64,8),dim3(256),0,stream>>>((const float*)(wsb+P1_B), (const char*)wsb, target,
           (float*)(wsb+SUMS_B), (float*)(wsb+L1P_B));
  kt2M<<<dim3(64,8),dim3(256),0,stream>>>((const float*)(wsb+P2_B), (const char*)wsb, target,
           (float*)(wsb+SUMS_B), (float*)(wsb+L2P_B));
  kfinal<<<dim3(1),dim3(256),0,stream>>>((const float*)(wsb+SUMS_B),
           (const float*)(wsb+HLT_B), (const float*)(wsb+HC1_B), (const float*)(wsb+HC2_B),
           (const float*)(wsb+L1P_B), (const float*)(wsb+L2P_B), target, outf);
}